// Round 4
// baseline (180.718 us; speedup 1.0000x reference)
//
#include <hip/hip_runtime.h>
#include <hip/hip_bf16.h>
#include <stdint.h>

#define Bz 2
#define Sz 2048
#define Dz 768
#define Hz 12
#define DHz 64
#define Mz (Bz*Sz)   // 4096

typedef __attribute__((ext_vector_type(4))) float f32x4;
typedef __attribute__((ext_vector_type(8))) short bf16x8;
typedef unsigned short u16;
typedef __attribute__((ext_vector_type(8))) unsigned short u16x8;

__device__ __forceinline__ u16 f2bf(float f) {
  union { float f; uint32_t u; } c; c.f = f;
  uint32_t u = c.u;
  return (u16)((u + 0x7fffu + ((u >> 16) & 1u)) >> 16);
}

#define GLL16(gsrc, ldst) \
  __builtin_amdgcn_global_load_lds((const __attribute__((address_space(1))) void*)(gsrc), \
                                   (__attribute__((address_space(3))) void*)(ldst), 16, 0, 0)

__device__ __forceinline__ f32x4 mfma16(bf16x8 a, bf16x8 b, f32x4 c) {
  return __builtin_amdgcn_mfma_f32_16x16x32_bf16(a, b, c, 0, 0, 0);
}

// ---------------- pre-pass: fp32 -> bf16 (q,k,v fused in one launch) ----------------
__global__ void cvt3_kernel(const float* __restrict__ qa, const float* __restrict__ ka,
                            const float* __restrict__ va,
                            u16* __restrict__ qo, u16* __restrict__ ko, u16* __restrict__ vo,
                            int n8) {
  int i = blockIdx.x * blockDim.x + threadIdx.x;
  if (i >= n8) return;
  int z = blockIdx.y;
  const float* src = (z == 0) ? qa : (z == 1) ? ka : va;
  u16* dst = (z == 0) ? qo : (z == 1) ? ko : vo;
  const float4* s4 = (const float4*)src;
  float4 a = s4[(size_t)i * 2];
  float4 b = s4[(size_t)i * 2 + 1];
  u16x8 o;
  o[0] = f2bf(a.x); o[1] = f2bf(a.y); o[2] = f2bf(a.z); o[3] = f2bf(a.w);
  o[4] = f2bf(b.x); o[5] = f2bf(b.y); o[6] = f2bf(b.z); o[7] = f2bf(b.w);
  *(u16x8*)(dst + (size_t)i * 8) = o;
}

// ---------------- pre-pass: W [K][N] fp32 -> Wt [N][K] bf16 (4 weights fused) ----------------
__global__ void wtrans4_kernel(const float* __restrict__ W0, const float* __restrict__ W1,
                               const float* __restrict__ W2, const float* __restrict__ W3,
                               u16* __restrict__ T0, u16* __restrict__ T1,
                               u16* __restrict__ T2, u16* __restrict__ T3) {
  __shared__ float tile[32][33];
  int z = blockIdx.z;
  const float* W = (z == 0) ? W0 : (z == 1) ? W1 : (z == 2) ? W2 : W3;
  u16* Wt = (z == 0) ? T0 : (z == 1) ? T1 : (z == 2) ? T2 : T3;
  int bx = blockIdx.x * 32, by = blockIdx.y * 32;
  int tx = threadIdx.x & 31, ty = threadIdx.x >> 5;   // 256 threads: ty 0..7
#pragma unroll
  for (int i = 0; i < 32; i += 8)
    tile[ty + i][tx] = W[(size_t)(by + ty + i) * Dz + bx + tx];
  __syncthreads();
#pragma unroll
  for (int i = 0; i < 32; i += 8)
    Wt[(size_t)(bx + ty + i) * Dz + by + tx] = f2bf(tile[tx][ty + i]);
}

// ---------------- GEMM core: C[M][N] = A[M][K] * Wt[N][K]^T + bias ----------------
// mode 0: bf16 out, layout [B,H,S,DH]   (Q, K projections)  (out = (acc+bias)*oscale)
// mode 1: bf16 out, layout [B,H,DH,S]   (V projection, transposed)
// mode 2: fp32 out, layout [M][N]       (final output projection)
__device__ __forceinline__ void gemm_core(
    const u16* __restrict__ A, const u16* __restrict__ Wt,
    const float* __restrict__ bias, void* __restrict__ out, int mode, float oscale,
    u16* As, u16* Bs)
{
  const int tid = threadIdx.x;
  const int wid = tid >> 6, lane = tid & 63;
  const int wm = wid >> 1, wn = wid & 1;
  const int m0 = blockIdx.x * 128, n0 = blockIdx.y * 128;
  const int fq = lane >> 4, fr = lane & 15;

  // staging source offsets (pre-swizzled so linear LDS dest + swizzled read match)
  int aoff[2];
#pragma unroll
  for (int c = 0; c < 2; ++c) {
    int off  = (wid * 2 + c) * 1024 + lane * 16;       // linear byte offset in 8KB tile
    int row  = off >> 6;                               // 64B rows (32 bf16)
    int colb = (off & 63) ^ (((row >> 1) & 3) << 4);   // XOR swizzle, bits 4-5
    aoff[c]  = row * Dz + (colb >> 1);                 // element offset (row stride K=768)
  }

  // fragment read byte-offsets
  int raddr[4], rbaddr[4];
#pragma unroll
  for (int f = 0; f < 4; ++f) {
    int rowA = wm * 64 + f * 16 + fr;
    raddr[f]  = rowA * 64 + ((fq * 16) ^ (((rowA >> 1) & 3) << 4));
    int rowB = wn * 64 + f * 16 + fr;
    rbaddr[f] = rowB * 64 + ((fq * 16) ^ (((rowB >> 1) & 3) << 4));
  }

  f32x4 acc[4][4];
  const f32x4 zero = {0.f, 0.f, 0.f, 0.f};
#pragma unroll
  for (int i = 0; i < 4; ++i)
#pragma unroll
    for (int j = 0; j < 4; ++j) acc[i][j] = zero;

  const u16* Abase = A + (size_t)m0 * Dz;
  const u16* Bbase = Wt + (size_t)n0 * Dz;

  for (int kt = 0; kt < Dz; kt += 32) {
#pragma unroll
    for (int c = 0; c < 2; ++c) {
      GLL16(Abase + kt + aoff[c], (char*)As + (wid * 2 + c) * 1024);
      GLL16(Bbase + kt + aoff[c], (char*)Bs + (wid * 2 + c) * 1024);
    }
    __syncthreads();
    bf16x8 af[4], bf[4];
#pragma unroll
    for (int f = 0; f < 4; ++f) {
      af[f] = *(const bf16x8*)((const char*)As + raddr[f]);
      bf[f] = *(const bf16x8*)((const char*)Bs + rbaddr[f]);
    }
    __builtin_amdgcn_s_setprio(1);
#pragma unroll
    for (int i = 0; i < 4; ++i)
#pragma unroll
      for (int j = 0; j < 4; ++j)
        acc[i][j] = mfma16(af[i], bf[j], acc[i][j]);
    __builtin_amdgcn_s_setprio(0);
    __syncthreads();
  }

  if (mode == 2) {
    float* O = (float*)out;
#pragma unroll
    for (int i = 0; i < 4; ++i) {
      int grow = m0 + wm * 64 + i * 16 + fq * 4;
#pragma unroll
      for (int j = 0; j < 4; ++j) {
        int gcol = n0 + wn * 64 + j * 16 + fr;
        float bv = bias[gcol];
#pragma unroll
        for (int r = 0; r < 4; ++r)
          O[(size_t)(grow + r) * Dz + gcol] = acc[i][j][r] + bv;
      }
    }
  } else {
    u16* O = (u16*)out;
#pragma unroll
    for (int i = 0; i < 4; ++i) {
      int grow = m0 + wm * 64 + i * 16 + fq * 4;
#pragma unroll
      for (int j = 0; j < 4; ++j) {
        int gcol = n0 + wn * 64 + j * 16 + fr;
        float bv = bias[gcol];
        int h = gcol >> 6, dh = gcol & 63;
#pragma unroll
        for (int r = 0; r < 4; ++r) {
          int t = grow + r;
          int b = t >> 11, s = t & 2047;
          float v = (acc[i][j][r] + bv) * oscale;
          if (mode == 0)
            O[((size_t)(b * Hz + h) * Sz + s) * DHz + dh] = f2bf(v);
          else
            O[((size_t)(b * Hz + h) * DHz + dh) * Sz + s] = f2bf(v);
        }
      }
    }
  }
}

// Q is pre-scaled by 1/sqrt(DH) * log2(e) so attention can use raw v_exp_f32 (exp2)
#define QSCALE 0.1803368801111404f   // 0.125 * 1.4426950408889634

__global__ __launch_bounds__(256, 2) void gemm_qkv(
    const u16* __restrict__ qb, const u16* __restrict__ kb, const u16* __restrict__ vb,
    const u16* __restrict__ Wqt, const u16* __restrict__ Wkt, const u16* __restrict__ Wvt,
    const float* __restrict__ bq, const float* __restrict__ bk, const float* __restrict__ bv,
    u16* __restrict__ Qh, u16* __restrict__ Kh, u16* __restrict__ Vt)
{
  __shared__ u16 As[128 * 32];
  __shared__ u16 Bs[128 * 32];
  const u16* A; const u16* W; const float* bias; u16* out; int mode; float osc;
  if (blockIdx.z == 0)      { A = qb; W = Wqt; bias = bq; out = Qh; mode = 0; osc = QSCALE; }
  else if (blockIdx.z == 1) { A = kb; W = Wkt; bias = bk; out = Kh; mode = 0; osc = 1.f; }
  else                      { A = vb; W = Wvt; bias = bv; out = Vt; mode = 1; osc = 1.f; }
  gemm_core(A, W, bias, out, mode, osc, As, Bs);
}

__global__ __launch_bounds__(256, 2) void gemm_out_k(
    const u16* __restrict__ ctx, const u16* __restrict__ Wot,
    const float* __restrict__ bo, float* __restrict__ out)
{
  __shared__ u16 As[128 * 32];
  __shared__ u16 Bs[128 * 32];
  gemm_core(ctx, Wot, bo, (void*)out, 2, 1.f, As, Bs);
}

// ---------------- flash attention, causal, BARRIER-FREE ----------------
// grid (B*H, S/64), block 256 (4 independent waves). bq = 31 - blockIdx.y (LPT).
// K/V read directly from global (L1/L2-resident working set: 512KB per head,
// ~1.5MB per XCD) into register fragments — no LDS staging, no __syncthreads.
// Only per-wave P round-trips through LDS (same-wave lgkmcnt, no barrier).
__global__ __launch_bounds__(256, 3) void attn_kernel(
    const u16* __restrict__ Qh, const u16* __restrict__ Kh,
    const u16* __restrict__ Vt, u16* __restrict__ ctx)
{
  __shared__ u16 Ps[4 * 16 * 64];   // 8 KB, per-wave scratch
  const int tid = threadIdx.x, wid = tid >> 6, lane = tid & 63;
  const int fq = lane >> 4, fr = lane & 15;
  const int bh = blockIdx.x;
  const int bq = (gridDim.y - 1) - blockIdx.y;   // global LPT: heaviest blocks dispatch first
  const int b = bh / Hz, h = bh % Hz;
  const int qbase = bq * 64 + wid * 16;

  // Q fragments (held for the whole kernel; pre-scaled by QSCALE at projection)
  const u16* Qg = Qh + ((size_t)bh * Sz + qbase) * DHz;
  bf16x8 aq[2];
#pragma unroll
  for (int kk = 0; kk < 2; ++kk)
    aq[kk] = *(const bf16x8*)(Qg + fr * DHz + kk * 32 + fq * 8);

  const f32x4 zero = {0.f, 0.f, 0.f, 0.f};
  f32x4 o[4];
#pragma unroll
  for (int i = 0; i < 4; ++i) o[i] = zero;
  float m_r[4], l_r[4];
#pragma unroll
  for (int r = 0; r < 4; ++r) { m_r[r] = -1e30f; l_r[r] = 0.f; }

  // per-lane fragment base pointers
  const u16* kp = Kh + (size_t)bh * Sz * DHz + fr * DHz + fq * 8;   // + kt*4096 + j*1024 + kk*32
  const u16* vp = Vt + (size_t)bh * DHz * Sz + fr * Sz + fq * 8;    // + fo*16*Sz + kt*64 + kk*32
  u16* Pw = Ps + wid * 16 * 64;
  const int nkt = bq + 1;

  bf16x8 kf[4][2];
#pragma unroll
  for (int j = 0; j < 4; ++j)
#pragma unroll
    for (int kk = 0; kk < 2; ++kk)
      kf[j][kk] = *(const bf16x8*)(kp + j * 1024 + kk * 32);

  for (int kt = 0; kt < nkt; ++kt) {
    // S = Q K^T   (already in log2-domain: Q pre-scaled by 0.125*log2e)
    f32x4 s[4];
#pragma unroll
    for (int j = 0; j < 4; ++j) s[j] = zero;
    __builtin_amdgcn_s_setprio(1);
#pragma unroll
    for (int j = 0; j < 4; ++j)
#pragma unroll
      for (int kk = 0; kk < 2; ++kk)
        s[j] = mfma16(aq[kk], kf[j][kk], s[j]);
    __builtin_amdgcn_s_setprio(0);

    // prefetch next tile's K fragments (hidden under softmax + PV)
    if (kt + 1 < nkt) {
      const u16* kn = kp + (size_t)(kt + 1) * 4096;
#pragma unroll
      for (int j = 0; j < 4; ++j)
#pragma unroll
        for (int kk = 0; kk < 2; ++kk)
          kf[j][kk] = *(const bf16x8*)(kn + j * 1024 + kk * 32);
    }

    // issue V fragment loads now (consumed after softmax — latency hidden)
    bf16x8 vf[4][2];
    {
      const u16* vn = vp + kt * 64;
#pragma unroll
      for (int fo = 0; fo < 4; ++fo)
#pragma unroll
        for (int kk = 0; kk < 2; ++kk)
          vf[fo][kk] = *(const bf16x8*)(vn + fo * 16 * Sz + kk * 32);
    }

    // causal mask: only the diagonal tile needs it (block-uniform branch)
    if (kt == bq) {
#pragma unroll
      for (int j = 0; j < 4; ++j) {
        int keyg = kt * 64 + j * 16 + fr;
#pragma unroll
        for (int r = 0; r < 4; ++r)
          if (keyg > qbase + fq * 4 + r) s[j][r] = -1e30f;
      }
    }

    // row max (16-lane butterfly within fr groups)
    float mt[4];
#pragma unroll
    for (int r = 0; r < 4; ++r) mt[r] = s[0][r];
#pragma unroll
    for (int j = 1; j < 4; ++j)
#pragma unroll
      for (int r = 0; r < 4; ++r) mt[r] = fmaxf(mt[r], s[j][r]);
#pragma unroll
    for (int msk = 1; msk < 16; msk <<= 1)
#pragma unroll
      for (int r = 0; r < 4; ++r) mt[r] = fmaxf(mt[r], __shfl_xor(mt[r], msk));

    // defer-max (T13, THR=8 in exp2 domain): rescale only when max grew enough
    int nd = 0;
#pragma unroll
    for (int r = 0; r < 4; ++r) nd |= (mt[r] > m_r[r] + 8.f) ? 1 : 0;
    if (__any(nd)) {
#pragma unroll
      for (int r = 0; r < 4; ++r) {
        float mn = fmaxf(m_r[r], mt[r]);
        float alpha = __builtin_amdgcn_exp2f(m_r[r] - mn);
        m_r[r] = mn;
        l_r[r] *= alpha;
#pragma unroll
        for (int i = 0; i < 4; ++i) o[i][r] *= alpha;
      }
    }

    // P = exp2(S - m), write to per-wave LDS (swizzled)
    float rs[4];
#pragma unroll
    for (int r = 0; r < 4; ++r) rs[r] = 0.f;
#pragma unroll
    for (int j = 0; j < 4; ++j) {
#pragma unroll
      for (int r = 0; r < 4; ++r) {
        float e = __builtin_amdgcn_exp2f(s[j][r] - m_r[r]);
        rs[r] += e;
        int qr = fq * 4 + r;
        int key2 = (j * 16 + fr) * 2;
        *(u16*)((char*)Pw + qr * 128 + (key2 ^ ((qr & 7) << 4))) = f2bf(e);
      }
    }
#pragma unroll
    for (int msk = 1; msk < 16; msk <<= 1)
#pragma unroll
      for (int r = 0; r < 4; ++r) rs[r] += __shfl_xor(rs[r], msk);
#pragma unroll
    for (int r = 0; r < 4; ++r) l_r[r] += rs[r];

    // O += P V   (P via per-wave LDS, V from registers)
    __builtin_amdgcn_s_setprio(1);
#pragma unroll
    for (int kk = 0; kk < 2; ++kk) {
      int cbP = (kk * 64 + fq * 16) ^ ((fr & 7) << 4);
      bf16x8 pa = *(const bf16x8*)((const char*)Pw + fr * 128 + cbP);
#pragma unroll
      for (int fo = 0; fo < 4; ++fo)
        o[fo] = mfma16(pa, vf[fo][kk], o[fo]);
    }
    __builtin_amdgcn_s_setprio(0);
  }

  // normalize + write ctx [B,S,D] bf16
#pragma unroll
  for (int fo = 0; fo < 4; ++fo) {
    int dh = fo * 16 + fr;
#pragma unroll
    for (int r = 0; r < 4; ++r) {
      int qg = qbase + fq * 4 + r;
      ctx[((size_t)b * Sz + qg) * Dz + h * DHz + dh] = f2bf(o[fo][r] / l_r[r]);
    }
  }
}

// ---------------- launch ----------------
extern "C" void kernel_launch(void* const* d_in, const int* in_sizes, int n_in,
                              void* d_out, int out_size, void* d_ws, size_t ws_size,
                              hipStream_t stream) {
  const float* q  = (const float*)d_in[0];
  const float* k  = (const float*)d_in[1];
  const float* v  = (const float*)d_in[2];
  const float* Wq = (const float*)d_in[3];
  const float* bq = (const float*)d_in[4];
  const float* Wk = (const float*)d_in[5];
  const float* bk = (const float*)d_in[6];
  const float* Wv = (const float*)d_in[7];
  const float* bv = (const float*)d_in[8];
  const float* Wo = (const float*)d_in[9];
  const float* bo = (const float*)d_in[10];
  float* out = (float*)d_out;

  char* ws = (char*)d_ws;
  size_t off = 0;
  auto alloc = [&](size_t bytes) {
    void* p = ws + off;
    off += (bytes + 255) & ~(size_t)255;
    return p;
  };
  u16* qb  = (u16*)alloc((size_t)Mz * Dz * 2);
  u16* kb  = (u16*)alloc((size_t)Mz * Dz * 2);
  u16* vb  = (u16*)alloc((size_t)Mz * Dz * 2);
  u16* Wqt = (u16*)alloc((size_t)Dz * Dz * 2);
  u16* Wkt = (u16*)alloc((size_t)Dz * Dz * 2);
  u16* Wvt = (u16*)alloc((size_t)Dz * Dz * 2);
  u16* Wot = (u16*)alloc((size_t)Dz * Dz * 2);
  u16* Qh  = (u16*)alloc((size_t)Bz * Hz * Sz * DHz * 2);
  u16* Kh  = (u16*)alloc((size_t)Bz * Hz * Sz * DHz * 2);
  u16* Vtr = (u16*)alloc((size_t)Bz * Hz * DHz * Sz * 2);
  u16* ctx = (u16*)alloc((size_t)Mz * Dz * 2);

  int n8 = Mz * Dz / 8;
  int cblk = (n8 + 255) / 256;
  cvt3_kernel<<<dim3(cblk, 3), 256, 0, stream>>>(q, k, v, qb, kb, vb, n8);

  wtrans4_kernel<<<dim3(Dz / 32, Dz / 32, 4), 256, 0, stream>>>(
      Wq, Wk, Wv, Wo, Wqt, Wkt, Wvt, Wot);

  gemm_qkv<<<dim3(Mz / 128, Dz / 128, 3), 256, 0, stream>>>(
      qb, kb, vb, Wqt, Wkt, Wvt, bq, bk, bv, Qh, Kh, Vtr);

  attn_kernel<<<dim3(Bz * Hz, Sz / 64), 256, 0, stream>>>(Qh, Kh, Vtr, ctx);

  gemm_out_k<<<dim3(Mz / 128, Dz / 128), 256, 0, stream>>>(ctx, Wot, bo, out);
}

// Round 5
// 160.220 us; speedup vs baseline: 1.1279x; 1.1279x over previous
//
#include <hip/hip_runtime.h>
#include <hip/hip_bf16.h>
#include <stdint.h>

#define Bz 2
#define Sz 2048
#define Dz 768
#define Hz 12
#define DHz 64
#define Mz (Bz*Sz)   // 4096

typedef __attribute__((ext_vector_type(4))) float f32x4;
typedef __attribute__((ext_vector_type(8))) short bf16x8;
typedef unsigned short u16;
typedef __attribute__((ext_vector_type(8))) unsigned short u16x8;

__device__ __forceinline__ u16 f2bf(float f) {
  union { float f; uint32_t u; } c; c.f = f;
  uint32_t u = c.u;
  return (u16)((u + 0x7fffu + ((u >> 16) & 1u)) >> 16);
}

#define GLL16(gsrc, ldst) \
  __builtin_amdgcn_global_load_lds((const __attribute__((address_space(1))) void*)(gsrc), \
                                   (__attribute__((address_space(3))) void*)(ldst), 16, 0, 0)

__device__ __forceinline__ f32x4 mfma16(bf16x8 a, bf16x8 b, f32x4 c) {
  return __builtin_amdgcn_mfma_f32_16x16x32_bf16(a, b, c, 0, 0, 0);
}

// ---------------- pre-pass: fp32 -> bf16 (q,k,v fused in one launch) ----------------
__global__ void cvt3_kernel(const float* __restrict__ qa, const float* __restrict__ ka,
                            const float* __restrict__ va,
                            u16* __restrict__ qo, u16* __restrict__ ko, u16* __restrict__ vo,
                            int n8) {
  int i = blockIdx.x * blockDim.x + threadIdx.x;
  if (i >= n8) return;
  int z = blockIdx.y;
  const float* src = (z == 0) ? qa : (z == 1) ? ka : va;
  u16* dst = (z == 0) ? qo : (z == 1) ? ko : vo;
  const float4* s4 = (const float4*)src;
  float4 a = s4[(size_t)i * 2];
  float4 b = s4[(size_t)i * 2 + 1];
  u16x8 o;
  o[0] = f2bf(a.x); o[1] = f2bf(a.y); o[2] = f2bf(a.z); o[3] = f2bf(a.w);
  o[4] = f2bf(b.x); o[5] = f2bf(b.y); o[6] = f2bf(b.z); o[7] = f2bf(b.w);
  *(u16x8*)(dst + (size_t)i * 8) = o;
}

// ---------------- pre-pass: W [K][N] fp32 -> Wt [N][K] bf16 (4 weights fused) ----------------
__global__ void wtrans4_kernel(const float* __restrict__ W0, const float* __restrict__ W1,
                               const float* __restrict__ W2, const float* __restrict__ W3,
                               u16* __restrict__ T0, u16* __restrict__ T1,
                               u16* __restrict__ T2, u16* __restrict__ T3) {
  __shared__ float tile[32][33];
  int z = blockIdx.z;
  const float* W = (z == 0) ? W0 : (z == 1) ? W1 : (z == 2) ? W2 : W3;
  u16* Wt = (z == 0) ? T0 : (z == 1) ? T1 : (z == 2) ? T2 : T3;
  int bx = blockIdx.x * 32, by = blockIdx.y * 32;
  int tx = threadIdx.x & 31, ty = threadIdx.x >> 5;   // 256 threads: ty 0..7
#pragma unroll
  for (int i = 0; i < 32; i += 8)
    tile[ty + i][tx] = W[(size_t)(by + ty + i) * Dz + bx + tx];
  __syncthreads();
#pragma unroll
  for (int i = 0; i < 32; i += 8)
    Wt[(size_t)(bx + ty + i) * Dz + by + tx] = f2bf(tile[tx][ty + i]);
}

// ---------------- GEMM core: C[M][N] = A[M][K] * Wt[N][K]^T + bias ----------------
// mode 0: bf16 out, layout [B,H,S,DH]   (Q, K projections)  (out = (acc+bias)*oscale)
// mode 1: bf16 out, layout [B,H,DH,S]   (V projection, transposed)
// mode 2: fp32 out, layout [M][N]       (final output projection)
__device__ __forceinline__ void gemm_core(
    const u16* __restrict__ A, const u16* __restrict__ Wt,
    const float* __restrict__ bias, void* __restrict__ out, int mode, float oscale,
    u16* As, u16* Bs)
{
  const int tid = threadIdx.x;
  const int wid = tid >> 6, lane = tid & 63;
  const int wm = wid >> 1, wn = wid & 1;
  const int m0 = blockIdx.x * 128, n0 = blockIdx.y * 128;
  const int fq = lane >> 4, fr = lane & 15;

  // staging source offsets (pre-swizzled so linear LDS dest + swizzled read match)
  int aoff[2];
#pragma unroll
  for (int c = 0; c < 2; ++c) {
    int off  = (wid * 2 + c) * 1024 + lane * 16;       // linear byte offset in 8KB tile
    int row  = off >> 6;                               // 64B rows (32 bf16)
    int colb = (off & 63) ^ (((row >> 1) & 3) << 4);   // XOR swizzle, bits 4-5
    aoff[c]  = row * Dz + (colb >> 1);                 // element offset (row stride K=768)
  }

  // fragment read byte-offsets
  int raddr[4], rbaddr[4];
#pragma unroll
  for (int f = 0; f < 4; ++f) {
    int rowA = wm * 64 + f * 16 + fr;
    raddr[f]  = rowA * 64 + ((fq * 16) ^ (((rowA >> 1) & 3) << 4));
    int rowB = wn * 64 + f * 16 + fr;
    rbaddr[f] = rowB * 64 + ((fq * 16) ^ (((rowB >> 1) & 3) << 4));
  }

  f32x4 acc[4][4];
  const f32x4 zero = {0.f, 0.f, 0.f, 0.f};
#pragma unroll
  for (int i = 0; i < 4; ++i)
#pragma unroll
    for (int j = 0; j < 4; ++j) acc[i][j] = zero;

  const u16* Abase = A + (size_t)m0 * Dz;
  const u16* Bbase = Wt + (size_t)n0 * Dz;

  for (int kt = 0; kt < Dz; kt += 32) {
#pragma unroll
    for (int c = 0; c < 2; ++c) {
      GLL16(Abase + kt + aoff[c], (char*)As + (wid * 2 + c) * 1024);
      GLL16(Bbase + kt + aoff[c], (char*)Bs + (wid * 2 + c) * 1024);
    }
    __syncthreads();
    bf16x8 af[4], bf[4];
#pragma unroll
    for (int f = 0; f < 4; ++f) {
      af[f] = *(const bf16x8*)((const char*)As + raddr[f]);
      bf[f] = *(const bf16x8*)((const char*)Bs + rbaddr[f]);
    }
    __builtin_amdgcn_s_setprio(1);
#pragma unroll
    for (int i = 0; i < 4; ++i)
#pragma unroll
      for (int j = 0; j < 4; ++j)
        acc[i][j] = mfma16(af[i], bf[j], acc[i][j]);
    __builtin_amdgcn_s_setprio(0);
    __syncthreads();
  }

  if (mode == 2) {
    float* O = (float*)out;
#pragma unroll
    for (int i = 0; i < 4; ++i) {
      int grow = m0 + wm * 64 + i * 16 + fq * 4;
#pragma unroll
      for (int j = 0; j < 4; ++j) {
        int gcol = n0 + wn * 64 + j * 16 + fr;
        float bv = bias[gcol];
#pragma unroll
        for (int r = 0; r < 4; ++r)
          O[(size_t)(grow + r) * Dz + gcol] = acc[i][j][r] + bv;
      }
    }
  } else {
    u16* O = (u16*)out;
#pragma unroll
    for (int i = 0; i < 4; ++i) {
      int grow = m0 + wm * 64 + i * 16 + fq * 4;
#pragma unroll
      for (int j = 0; j < 4; ++j) {
        int gcol = n0 + wn * 64 + j * 16 + fr;
        float bv = bias[gcol];
        int h = gcol >> 6, dh = gcol & 63;
#pragma unroll
        for (int r = 0; r < 4; ++r) {
          int t = grow + r;
          int b = t >> 11, s = t & 2047;
          float v = (acc[i][j][r] + bv) * oscale;
          if (mode == 0)
            O[((size_t)(b * Hz + h) * Sz + s) * DHz + dh] = f2bf(v);
          else
            O[((size_t)(b * Hz + h) * DHz + dh) * Sz + s] = f2bf(v);
        }
      }
    }
  }
}

// Q is pre-scaled by 1/sqrt(DH) * log2(e) so attention can use raw v_exp_f32 (exp2)
#define QSCALE 0.1803368801111404f   // 0.125 * 1.4426950408889634

__global__ __launch_bounds__(256, 2) void gemm_qkv(
    const u16* __restrict__ qb, const u16* __restrict__ kb, const u16* __restrict__ vb,
    const u16* __restrict__ Wqt, const u16* __restrict__ Wkt, const u16* __restrict__ Wvt,
    const float* __restrict__ bq, const float* __restrict__ bk, const float* __restrict__ bv,
    u16* __restrict__ Qh, u16* __restrict__ Kh, u16* __restrict__ Vt)
{
  __shared__ u16 As[128 * 32];
  __shared__ u16 Bs[128 * 32];
  const u16* A; const u16* W; const float* bias; u16* out; int mode; float osc;
  if (blockIdx.z == 0)      { A = qb; W = Wqt; bias = bq; out = Qh; mode = 0; osc = QSCALE; }
  else if (blockIdx.z == 1) { A = kb; W = Wkt; bias = bk; out = Kh; mode = 0; osc = 1.f; }
  else                      { A = vb; W = Wvt; bias = bv; out = Vt; mode = 1; osc = 1.f; }
  gemm_core(A, W, bias, out, mode, osc, As, Bs);
}

__global__ __launch_bounds__(256, 2) void gemm_out_k(
    const u16* __restrict__ ctx, const u16* __restrict__ Wot,
    const float* __restrict__ bo, float* __restrict__ out)
{
  __shared__ u16 As[128 * 32];
  __shared__ u16 Bs[128 * 32];
  gemm_core(ctx, Wot, bo, (void*)out, 2, 1.f, As, Bs);
}

// ---------------- flash attention, causal ----------------
// grid (B*H, S/128), block 256 (4 waves x 32 q-rows). bq = 15 - blockIdx.y (LPT).
// K/V staged via global_load_lds, double-buffered. Per-wave softmax state is
// fully deferred: no cross-lane reduce in the steady-state loop (defer-max
// trigger check is per-lane; l kept as per-lane partials, reduced once at end).
__device__ __forceinline__ void stage_kv(const u16* __restrict__ Kg, const u16* __restrict__ Vg,
                                         int kt, u16* Ks, u16* Vs, int wid, int lane) {
#pragma unroll
  for (int c = 0; c < 2; ++c) {
    int off  = (wid * 2 + c) * 1024 + lane * 16;
    int row  = off >> 7;                       // 128B rows (64 bf16)
    int colb = (off & 127) ^ ((row & 7) << 4); // XOR swizzle bits 4-6
    GLL16(Kg + ((size_t)(kt * 64 + row)) * DHz + (colb >> 1), (char*)Ks + (wid * 2 + c) * 1024);
    GLL16(Vg + (size_t)row * Sz + kt * 64 + (colb >> 1),      (char*)Vs + (wid * 2 + c) * 1024);
  }
}

__global__ __launch_bounds__(256, 3) void attn_kernel(
    const u16* __restrict__ Qh, const u16* __restrict__ Kh,
    const u16* __restrict__ Vt, u16* __restrict__ ctx)
{
  __shared__ u16 Ks[2][64 * 64];   // 16 KB
  __shared__ u16 Vs[2][64 * 64];   // 16 KB
  __shared__ u16 Ps[4 * 32 * 64];  // 16 KB (per-wave 32x64 P tile)
  const int tid = threadIdx.x, wid = tid >> 6, lane = tid & 63;
  const int fq = lane >> 4, fr = lane & 15;
  const int bh = blockIdx.x;
  const int bq = (gridDim.y - 1) - blockIdx.y;   // global LPT: heaviest blocks first
  const int b = bh / Hz, h = bh % Hz;
  const int qbase = bq * 128 + wid * 32;         // wave's first q-row
  const int kd = qbase >> 6;                     // wave's diagonal tile

  // Q fragments: 2 row-groups of 16 (pre-scaled by QSCALE at projection)
  const u16* Qg = Qh + ((size_t)bh * Sz + qbase) * DHz;
  bf16x8 aq[2][2];
#pragma unroll
  for (int g = 0; g < 2; ++g)
#pragma unroll
    for (int kk = 0; kk < 2; ++kk)
      aq[g][kk] = *(const bf16x8*)(Qg + (g * 16 + fr) * DHz + kk * 32 + fq * 8);

  const f32x4 zero = {0.f, 0.f, 0.f, 0.f};
  f32x4 o[2][4];
#pragma unroll
  for (int g = 0; g < 2; ++g)
#pragma unroll
    for (int i = 0; i < 4; ++i) o[g][i] = zero;
  float m_r[2][4], l_r[2][4];
#pragma unroll
  for (int g = 0; g < 2; ++g)
#pragma unroll
    for (int r = 0; r < 4; ++r) { m_r[g][r] = -1e30f; l_r[g][r] = 0.f; }

  const u16* Kg = Kh + (size_t)bh * Sz * DHz;
  const u16* Vg = Vt + (size_t)bh * DHz * Sz;
  u16* Pw = Ps + wid * 32 * 64;
  const int nkt = 2 * bq + 2;

  stage_kv(Kg, Vg, 0, Ks[0], Vs[0], wid, lane);
  int cur = 0;

  for (int kt = 0; kt < nkt; ++kt) {
    __syncthreads();   // buf[cur] staging drained; prev tile's LDS reads complete
    if (kt + 1 < nkt)
      stage_kv(Kg, Vg, kt + 1, Ks[cur ^ 1], Vs[cur ^ 1], wid, lane);

    if (kt <= kd) {    // wave-uniform: skip tiles fully above this wave's diagonal
      const char* Kb = (const char*)Ks[cur];
      const char* Vb = (const char*)Vs[cur];

      // K fragments (shared by both row-groups)
      bf16x8 kfr[4][2];
#pragma unroll
      for (int j = 0; j < 4; ++j) {
        int rowK = j * 16 + fr;
#pragma unroll
        for (int kk = 0; kk < 2; ++kk)
          kfr[j][kk] = *(const bf16x8*)(Kb + rowK * 128 + ((kk * 64 + fq * 16) ^ ((rowK & 7) << 4)));
      }

      // S = Q K^T  (log2-domain)
      f32x4 s[2][4];
#pragma unroll
      for (int g = 0; g < 2; ++g)
#pragma unroll
        for (int j = 0; j < 4; ++j) s[g][j] = zero;
      __builtin_amdgcn_s_setprio(1);
#pragma unroll
      for (int g = 0; g < 2; ++g)
#pragma unroll
        for (int j = 0; j < 4; ++j)
#pragma unroll
          for (int kk = 0; kk < 2; ++kk)
            s[g][j] = mfma16(aq[g][kk], kfr[j][kk], s[g][j]);
      __builtin_amdgcn_s_setprio(0);

      // V fragments (shared by both row-groups) — issue early to hide LDS latency
      bf16x8 vfr[4][2];
#pragma unroll
      for (int fo = 0; fo < 4; ++fo) {
        int rowV = fo * 16 + fr;
#pragma unroll
        for (int kk = 0; kk < 2; ++kk)
          vfr[fo][kk] = *(const bf16x8*)(Vb + rowV * 128 + ((kk * 64 + fq * 16) ^ ((rowV & 7) << 4)));
      }

      // causal mask on the wave's single diagonal tile
      if (kt == kd) {
#pragma unroll
        for (int g = 0; g < 2; ++g)
#pragma unroll
          for (int j = 0; j < 4; ++j) {
            int keyg = kt * 64 + j * 16 + fr;
#pragma unroll
            for (int r = 0; r < 4; ++r)
              if (keyg > qbase + g * 16 + fq * 4 + r) s[g][j][r] = -1e30f;
          }
      }

      // per-lane partial row max (no cross-lane reduce in steady state)
      float mt[2][4];
#pragma unroll
      for (int g = 0; g < 2; ++g) {
#pragma unroll
        for (int r = 0; r < 4; ++r) mt[g][r] = s[g][0][r];
#pragma unroll
        for (int j = 1; j < 4; ++j)
#pragma unroll
          for (int r = 0; r < 4; ++r) mt[g][r] = fmaxf(mt[g][r], s[g][j][r]);
      }

      // defer-max trigger: per-lane check, butterfly+rescale only when needed
      int nd = 0;
#pragma unroll
      for (int g = 0; g < 2; ++g)
#pragma unroll
        for (int r = 0; r < 4; ++r) nd |= (mt[g][r] > m_r[g][r] + 8.f) ? 1 : 0;
      if (__any(nd)) {
#pragma unroll
        for (int msk = 1; msk < 16; msk <<= 1)
#pragma unroll
          for (int g = 0; g < 2; ++g)
#pragma unroll
            for (int r = 0; r < 4; ++r)
              mt[g][r] = fmaxf(mt[g][r], __shfl_xor(mt[g][r], msk));
#pragma unroll
        for (int g = 0; g < 2; ++g)
#pragma unroll
          for (int r = 0; r < 4; ++r) {
            float mn = fmaxf(m_r[g][r], mt[g][r]);
            float alpha = __builtin_amdgcn_exp2f(m_r[g][r] - mn);
            m_r[g][r] = mn;
            l_r[g][r] *= alpha;
#pragma unroll
            for (int i = 0; i < 4; ++i) o[g][i][r] *= alpha;
          }
      }

      // P = exp2(S - m); accumulate per-lane partial l; write P to per-wave LDS
#pragma unroll
      for (int g = 0; g < 2; ++g)
#pragma unroll
        for (int j = 0; j < 4; ++j) {
#pragma unroll
          for (int r = 0; r < 4; ++r) {
            float e = __builtin_amdgcn_exp2f(s[g][j][r] - m_r[g][r]);
            l_r[g][r] += e;
            int qr = g * 16 + fq * 4 + r;
            int key2 = (j * 16 + fr) * 2;
            *(u16*)((char*)Pw + qr * 128 + (key2 ^ ((qr & 7) << 4))) = f2bf(e);
          }
        }

      // O += P V
      __builtin_amdgcn_s_setprio(1);
#pragma unroll
      for (int g = 0; g < 2; ++g)
#pragma unroll
        for (int kk = 0; kk < 2; ++kk) {
          int rowP = g * 16 + fr;
          int cbP = (kk * 64 + fq * 16) ^ ((rowP & 7) << 4);
          bf16x8 pa = *(const bf16x8*)((const char*)Pw + rowP * 128 + cbP);
#pragma unroll
          for (int fo = 0; fo < 4; ++fo)
            o[g][fo] = mfma16(pa, vfr[fo][kk], o[g][fo]);
        }
      __builtin_amdgcn_s_setprio(0);
    }
    cur ^= 1;
  }

  // final l reduce (once) + normalize + write ctx [B,S,D] bf16
#pragma unroll
  for (int msk = 1; msk < 16; msk <<= 1)
#pragma unroll
    for (int g = 0; g < 2; ++g)
#pragma unroll
      for (int r = 0; r < 4; ++r) l_r[g][r] += __shfl_xor(l_r[g][r], msk);

#pragma unroll
  for (int g = 0; g < 2; ++g)
#pragma unroll
    for (int fo = 0; fo < 4; ++fo) {
      int dh = fo * 16 + fr;
#pragma unroll
      for (int r = 0; r < 4; ++r) {
        int qg = qbase + g * 16 + fq * 4 + r;
        ctx[((size_t)b * Sz + qg) * Dz + h * DHz + dh] = f2bf(o[g][fo][r] / l_r[g][r]);
      }
    }
}

// ---------------- launch ----------------
extern "C" void kernel_launch(void* const* d_in, const int* in_sizes, int n_in,
                              void* d_out, int out_size, void* d_ws, size_t ws_size,
                              hipStream_t stream) {
  const float* q  = (const float*)d_in[0];
  const float* k  = (const float*)d_in[1];
  const float* v  = (const float*)d_in[2];
  const float* Wq = (const float*)d_in[3];
  const float* bq = (const float*)d_in[4];
  const float* Wk = (const float*)d_in[5];
  const float* bk = (const float*)d_in[6];
  const float* Wv = (const float*)d_in[7];
  const float* bv = (const float*)d_in[8];
  const float* Wo = (const float*)d_in[9];
  const float* bo = (const float*)d_in[10];
  float* out = (float*)d_out;

  char* ws = (char*)d_ws;
  size_t off = 0;
  auto alloc = [&](size_t bytes) {
    void* p = ws + off;
    off += (bytes + 255) & ~(size_t)255;
    return p;
  };
  u16* qb  = (u16*)alloc((size_t)Mz * Dz * 2);
  u16* kb  = (u16*)alloc((size_t)Mz * Dz * 2);
  u16* vb  = (u16*)alloc((size_t)Mz * Dz * 2);
  u16* Wqt = (u16*)alloc((size_t)Dz * Dz * 2);
  u16* Wkt = (u16*)alloc((size_t)Dz * Dz * 2);
  u16* Wvt = (u16*)alloc((size_t)Dz * Dz * 2);
  u16* Wot = (u16*)alloc((size_t)Dz * Dz * 2);
  u16* Qh  = (u16*)alloc((size_t)Bz * Hz * Sz * DHz * 2);
  u16* Kh  = (u16*)alloc((size_t)Bz * Hz * Sz * DHz * 2);
  u16* Vtr = (u16*)alloc((size_t)Bz * Hz * DHz * Sz * 2);
  u16* ctx = (u16*)alloc((size_t)Mz * Dz * 2);

  int n8 = Mz * Dz / 8;
  int cblk = (n8 + 255) / 256;
  cvt3_kernel<<<dim3(cblk, 3), 256, 0, stream>>>(q, k, v, qb, kb, vb, n8);

  wtrans4_kernel<<<dim3(Dz / 32, Dz / 32, 4), 256, 0, stream>>>(
      Wq, Wk, Wv, Wo, Wqt, Wkt, Wvt, Wot);

  gemm_qkv<<<dim3(Mz / 128, Dz / 128, 3), 256, 0, stream>>>(
      qb, kb, vb, Wqt, Wkt, Wvt, bq, bk, bv, Qh, Kh, Vtr);

  attn_kernel<<<dim3(Bz * Hz, Sz / 128), 256, 0, stream>>>(Qh, Kh, Vtr, ctx);

  gemm_out_k<<<dim3(Mz / 128, Dz / 128), 256, 0, stream>>>(ctx, Wot, bo, out);
}

// Round 6
// 137.195 us; speedup vs baseline: 1.3172x; 1.1678x over previous
//
#include <hip/hip_runtime.h>
#include <hip/hip_bf16.h>
#include <stdint.h>

#define Bz 2
#define Sz 2048
#define Dz 768
#define Hz 12
#define DHz 64
#define Mz (Bz*Sz)   // 4096
#define NQT (Sz/64)          // 32 q-tiles per (b,h)
#define NITEMS (Bz*Hz*NQT)   // 768 work items

typedef __attribute__((ext_vector_type(4))) float f32x4;
typedef __attribute__((ext_vector_type(8))) short bf16x8;
typedef unsigned short u16;
typedef __attribute__((ext_vector_type(8))) unsigned short u16x8;

__device__ __forceinline__ u16 f2bf(float f) {
  union { float f; uint32_t u; } c; c.f = f;
  uint32_t u = c.u;
  return (u16)((u + 0x7fffu + ((u >> 16) & 1u)) >> 16);
}

#define GLL16(gsrc, ldst) \
  __builtin_amdgcn_global_load_lds((const __attribute__((address_space(1))) void*)(gsrc), \
                                   (__attribute__((address_space(3))) void*)(ldst), 16, 0, 0)

__device__ __forceinline__ f32x4 mfma16(bf16x8 a, bf16x8 b, f32x4 c) {
  return __builtin_amdgcn_mfma_f32_16x16x32_bf16(a, b, c, 0, 0, 0);
}

// ---------------- pre-pass: fp32 -> bf16 (q,k,v fused; also zeroes work counter) ----------------
__global__ void cvt3_kernel(const float* __restrict__ qa, const float* __restrict__ ka,
                            const float* __restrict__ va,
                            u16* __restrict__ qo, u16* __restrict__ ko, u16* __restrict__ vo,
                            int n8, int* __restrict__ counter) {
  if (blockIdx.x == 0 && blockIdx.y == 0 && threadIdx.x == 0) *counter = 0;
  int i = blockIdx.x * blockDim.x + threadIdx.x;
  if (i >= n8) return;
  int z = blockIdx.y;
  const float* src = (z == 0) ? qa : (z == 1) ? ka : va;
  u16* dst = (z == 0) ? qo : (z == 1) ? ko : vo;
  const float4* s4 = (const float4*)src;
  float4 a = s4[(size_t)i * 2];
  float4 b = s4[(size_t)i * 2 + 1];
  u16x8 o;
  o[0] = f2bf(a.x); o[1] = f2bf(a.y); o[2] = f2bf(a.z); o[3] = f2bf(a.w);
  o[4] = f2bf(b.x); o[5] = f2bf(b.y); o[6] = f2bf(b.z); o[7] = f2bf(b.w);
  *(u16x8*)(dst + (size_t)i * 8) = o;
}

// ---------------- pre-pass: W [K][N] fp32 -> Wt [N][K] bf16 (4 weights fused) ----------------
__global__ void wtrans4_kernel(const float* __restrict__ W0, const float* __restrict__ W1,
                               const float* __restrict__ W2, const float* __restrict__ W3,
                               u16* __restrict__ T0, u16* __restrict__ T1,
                               u16* __restrict__ T2, u16* __restrict__ T3) {
  __shared__ float tile[32][33];
  int z = blockIdx.z;
  const float* W = (z == 0) ? W0 : (z == 1) ? W1 : (z == 2) ? W2 : W3;
  u16* Wt = (z == 0) ? T0 : (z == 1) ? T1 : (z == 2) ? T2 : T3;
  int bx = blockIdx.x * 32, by = blockIdx.y * 32;
  int tx = threadIdx.x & 31, ty = threadIdx.x >> 5;   // 256 threads: ty 0..7
#pragma unroll
  for (int i = 0; i < 32; i += 8)
    tile[ty + i][tx] = W[(size_t)(by + ty + i) * Dz + bx + tx];
  __syncthreads();
#pragma unroll
  for (int i = 0; i < 32; i += 8)
    Wt[(size_t)(bx + ty + i) * Dz + by + tx] = f2bf(tile[tx][ty + i]);
}

// ---------------- GEMM core: C[M][N] = A[M][K] * Wt[N][K]^T + bias ----------------
// mode 0: bf16 out, layout [B,H,S,DH]   (Q, K projections)  (out = (acc+bias)*oscale)
// mode 1: bf16 out, layout [B,H,DH,S]   (V projection, transposed)
// mode 2: fp32 out, layout [M][N]       (final output projection)
__device__ __forceinline__ void gemm_core(
    const u16* __restrict__ A, const u16* __restrict__ Wt,
    const float* __restrict__ bias, void* __restrict__ out, int mode, float oscale,
    u16* As, u16* Bs)
{
  const int tid = threadIdx.x;
  const int wid = tid >> 6, lane = tid & 63;
  const int wm = wid >> 1, wn = wid & 1;
  const int m0 = blockIdx.x * 128, n0 = blockIdx.y * 128;
  const int fq = lane >> 4, fr = lane & 15;

  // staging source offsets (pre-swizzled so linear LDS dest + swizzled read match)
  int aoff[2];
#pragma unroll
  for (int c = 0; c < 2; ++c) {
    int off  = (wid * 2 + c) * 1024 + lane * 16;       // linear byte offset in 8KB tile
    int row  = off >> 6;                               // 64B rows (32 bf16)
    int colb = (off & 63) ^ (((row >> 1) & 3) << 4);   // XOR swizzle, bits 4-5
    aoff[c]  = row * Dz + (colb >> 1);                 // element offset (row stride K=768)
  }

  // fragment read byte-offsets
  int raddr[4], rbaddr[4];
#pragma unroll
  for (int f = 0; f < 4; ++f) {
    int rowA = wm * 64 + f * 16 + fr;
    raddr[f]  = rowA * 64 + ((fq * 16) ^ (((rowA >> 1) & 3) << 4));
    int rowB = wn * 64 + f * 16 + fr;
    rbaddr[f] = rowB * 64 + ((fq * 16) ^ (((rowB >> 1) & 3) << 4));
  }

  f32x4 acc[4][4];
  const f32x4 zero = {0.f, 0.f, 0.f, 0.f};
#pragma unroll
  for (int i = 0; i < 4; ++i)
#pragma unroll
    for (int j = 0; j < 4; ++j) acc[i][j] = zero;

  const u16* Abase = A + (size_t)m0 * Dz;
  const u16* Bbase = Wt + (size_t)n0 * Dz;

  for (int kt = 0; kt < Dz; kt += 32) {
#pragma unroll
    for (int c = 0; c < 2; ++c) {
      GLL16(Abase + kt + aoff[c], (char*)As + (wid * 2 + c) * 1024);
      GLL16(Bbase + kt + aoff[c], (char*)Bs + (wid * 2 + c) * 1024);
    }
    __syncthreads();
    bf16x8 af[4], bf[4];
#pragma unroll
    for (int f = 0; f < 4; ++f) {
      af[f] = *(const bf16x8*)((const char*)As + raddr[f]);
      bf[f] = *(const bf16x8*)((const char*)Bs + rbaddr[f]);
    }
    __builtin_amdgcn_s_setprio(1);
#pragma unroll
    for (int i = 0; i < 4; ++i)
#pragma unroll
      for (int j = 0; j < 4; ++j)
        acc[i][j] = mfma16(af[i], bf[j], acc[i][j]);
    __builtin_amdgcn_s_setprio(0);
    __syncthreads();
  }

  if (mode == 2) {
    float* O = (float*)out;
#pragma unroll
    for (int i = 0; i < 4; ++i) {
      int grow = m0 + wm * 64 + i * 16 + fq * 4;
#pragma unroll
      for (int j = 0; j < 4; ++j) {
        int gcol = n0 + wn * 64 + j * 16 + fr;
        float bv = bias[gcol];
#pragma unroll
        for (int r = 0; r < 4; ++r)
          O[(size_t)(grow + r) * Dz + gcol] = acc[i][j][r] + bv;
      }
    }
  } else {
    u16* O = (u16*)out;
#pragma unroll
    for (int i = 0; i < 4; ++i) {
      int grow = m0 + wm * 64 + i * 16 + fq * 4;
#pragma unroll
      for (int j = 0; j < 4; ++j) {
        int gcol = n0 + wn * 64 + j * 16 + fr;
        float bv = bias[gcol];
        int h = gcol >> 6, dh = gcol & 63;
#pragma unroll
        for (int r = 0; r < 4; ++r) {
          int t = grow + r;
          int b = t >> 11, s = t & 2047;
          float v = (acc[i][j][r] + bv) * oscale;
          if (mode == 0)
            O[((size_t)(b * Hz + h) * Sz + s) * DHz + dh] = f2bf(v);
          else
            O[((size_t)(b * Hz + h) * DHz + dh) * Sz + s] = f2bf(v);
        }
      }
    }
  }
}

// Q is pre-scaled by 1/sqrt(DH) * log2(e) so attention can use raw v_exp_f32 (exp2)
#define QSCALE 0.1803368801111404f   // 0.125 * 1.4426950408889634

__global__ __launch_bounds__(256, 2) void gemm_qkv(
    const u16* __restrict__ qb, const u16* __restrict__ kb, const u16* __restrict__ vb,
    const u16* __restrict__ Wqt, const u16* __restrict__ Wkt, const u16* __restrict__ Wvt,
    const float* __restrict__ bq, const float* __restrict__ bk, const float* __restrict__ bv,
    u16* __restrict__ Qh, u16* __restrict__ Kh, u16* __restrict__ Vt)
{
  __shared__ u16 As[128 * 32];
  __shared__ u16 Bs[128 * 32];
  const u16* A; const u16* W; const float* bias; u16* out; int mode; float osc;
  if (blockIdx.z == 0)      { A = qb; W = Wqt; bias = bq; out = Qh; mode = 0; osc = QSCALE; }
  else if (blockIdx.z == 1) { A = kb; W = Wkt; bias = bk; out = Kh; mode = 0; osc = 1.f; }
  else                      { A = vb; W = Wvt; bias = bv; out = Vt; mode = 1; osc = 1.f; }
  gemm_core(A, W, bias, out, mode, osc, As, Bs);
}

__global__ __launch_bounds__(256, 2) void gemm_out_k(
    const u16* __restrict__ ctx, const u16* __restrict__ Wot,
    const float* __restrict__ bo, float* __restrict__ out)
{
  __shared__ u16 As[128 * 32];
  __shared__ u16 Bs[128 * 32];
  gemm_core(ctx, Wot, bo, (void*)out, 2, 1.f, As, Bs);
}

// ---------------- flash attention, causal, PERSISTENT ----------------
// 1024 persistent blocks (4/CU, 40KB LDS each = full 160KB pool). Work items =
// (bh, bq) q-tiles pulled from a global atomic counter in heavy-first order, so
// every CU keeps 4 blocks overlapping until the queue drains (tail = 1-tile items).
// Per item: R3 structure (4 waves x 16 q-rows, 64-key tiles, double-buffered
// global_load_lds staging) + fully deferred softmax (no cross-lane reduce in
// steady state; l reduced once at the end).
__device__ __forceinline__ void stage_kv(const u16* __restrict__ Kg, const u16* __restrict__ Vg,
                                         int kt, u16* Ks, u16* Vs, int wid, int lane) {
#pragma unroll
  for (int c = 0; c < 2; ++c) {
    int off  = (wid * 2 + c) * 1024 + lane * 16;
    int row  = off >> 7;                       // 128B rows (64 bf16)
    int colb = (off & 127) ^ ((row & 7) << 4); // XOR swizzle bits 4-6
    GLL16(Kg + ((size_t)(kt * 64 + row)) * DHz + (colb >> 1), (char*)Ks + (wid * 2 + c) * 1024);
    GLL16(Vg + (size_t)row * Sz + kt * 64 + (colb >> 1),      (char*)Vs + (wid * 2 + c) * 1024);
  }
}

__global__ __launch_bounds__(256, 4) void attn_kernel(
    const u16* __restrict__ Qh, const u16* __restrict__ Kh,
    const u16* __restrict__ Vt, u16* __restrict__ ctx, int* __restrict__ counter)
{
  __shared__ u16 Ks[2][64 * 64];   // 16 KB
  __shared__ u16 Vs[2][64 * 64];   // 16 KB
  __shared__ u16 Ps[4 * 16 * 64];  //  8 KB (per-wave 16x64 P tile)
  int* s_item = (int*)Ps;          // aliased: only used at item boundaries

  const int tid = threadIdx.x, wid = tid >> 6, lane = tid & 63;
  const int fq = lane >> 4, fr = lane & 15;
  const f32x4 zero = {0.f, 0.f, 0.f, 0.f};
  u16* Pw = Ps + wid * 16 * 64;

  for (;;) {
    if (tid == 0) *s_item = atomicAdd(counter, 1);
    __syncthreads();
    const int t = *s_item;
    if (t >= NITEMS) break;

    // heavy-first mapping: rank rk -> bq = 31-rk (32 tiles first, 1 tile last)
    const int rk = t / (Bz * Hz);
    const int bh = t - rk * (Bz * Hz);
    const int bq = (NQT - 1) - rk;
    const int b = bh / Hz, h = bh % Hz;
    const int qbase = bq * 64 + wid * 16;
    const int nkt = bq + 1;

    const u16* Kg = Kh + (size_t)bh * Sz * DHz;
    const u16* Vg = Vt + (size_t)bh * DHz * Sz;
    const u16* Qg = Qh + ((size_t)bh * Sz + qbase) * DHz;

    bf16x8 aq[2];
#pragma unroll
    for (int kk = 0; kk < 2; ++kk)
      aq[kk] = *(const bf16x8*)(Qg + fr * DHz + kk * 32 + fq * 8);

    f32x4 o[4];
#pragma unroll
    for (int i = 0; i < 4; ++i) o[i] = zero;
    float m_r[4], l_r[4];
#pragma unroll
    for (int r = 0; r < 4; ++r) { m_r[r] = -1e30f; l_r[r] = 0.f; }

    stage_kv(Kg, Vg, 0, Ks[0], Vs[0], wid, lane);
    int cur = 0;

    for (int kt = 0; kt < nkt; ++kt) {
      __syncthreads();   // buf[cur] staging drained; prev tile's LDS reads complete
      if (kt + 1 < nkt)
        stage_kv(Kg, Vg, kt + 1, Ks[cur ^ 1], Vs[cur ^ 1], wid, lane);

      const char* Kb = (const char*)Ks[cur];
      const char* Vb = (const char*)Vs[cur];

      // K fragments
      bf16x8 kfr_[4][2];
#pragma unroll
      for (int j = 0; j < 4; ++j) {
        int rowK = j * 16 + fr;
#pragma unroll
        for (int kk = 0; kk < 2; ++kk)
          kfr_[j][kk] = *(const bf16x8*)(Kb + rowK * 128 + ((kk * 64 + fq * 16) ^ ((rowK & 7) << 4)));
      }

      // S = Q K^T  (log2-domain: Q pre-scaled by 0.125*log2e)
      f32x4 s[4];
#pragma unroll
      for (int j = 0; j < 4; ++j) s[j] = zero;
      __builtin_amdgcn_s_setprio(1);
#pragma unroll
      for (int j = 0; j < 4; ++j)
#pragma unroll
        for (int kk = 0; kk < 2; ++kk)
          s[j] = mfma16(aq[kk], kfr_[j][kk], s[j]);
      __builtin_amdgcn_s_setprio(0);

      // V fragments — issue early to hide LDS latency under softmax
      bf16x8 vfr_[4][2];
#pragma unroll
      for (int fo = 0; fo < 4; ++fo) {
        int rowV = fo * 16 + fr;
#pragma unroll
        for (int kk = 0; kk < 2; ++kk)
          vfr_[fo][kk] = *(const bf16x8*)(Vb + rowV * 128 + ((kk * 64 + fq * 16) ^ ((rowV & 7) << 4)));
      }

      // causal mask: only on the diagonal tile (block-uniform branch)
      if (kt == bq) {
#pragma unroll
        for (int j = 0; j < 4; ++j) {
          int keyg = kt * 64 + j * 16 + fr;
#pragma unroll
          for (int r = 0; r < 4; ++r)
            if (keyg > qbase + fq * 4 + r) s[j][r] = -1e30f;
        }
      }

      // per-lane partial row max (no cross-lane reduce unless triggered)
      float mt[4];
#pragma unroll
      for (int r = 0; r < 4; ++r) mt[r] = s[0][r];
#pragma unroll
      for (int j = 1; j < 4; ++j)
#pragma unroll
        for (int r = 0; r < 4; ++r) mt[r] = fmaxf(mt[r], s[j][r]);

      int nd = 0;
#pragma unroll
      for (int r = 0; r < 4; ++r) nd |= (mt[r] > m_r[r] + 8.f) ? 1 : 0;
      if (__any(nd)) {
#pragma unroll
        for (int msk = 1; msk < 16; msk <<= 1)
#pragma unroll
          for (int r = 0; r < 4; ++r) mt[r] = fmaxf(mt[r], __shfl_xor(mt[r], msk));
#pragma unroll
        for (int r = 0; r < 4; ++r) {
          float mn = fmaxf(m_r[r], mt[r]);
          float alpha = __builtin_amdgcn_exp2f(m_r[r] - mn);
          m_r[r] = mn;
          l_r[r] *= alpha;
#pragma unroll
          for (int i = 0; i < 4; ++i) o[i][r] *= alpha;
        }
      }

      // P = exp2(S - m); per-lane partial l; write P to per-wave LDS (swizzled)
#pragma unroll
      for (int j = 0; j < 4; ++j) {
#pragma unroll
        for (int r = 0; r < 4; ++r) {
          float e = __builtin_amdgcn_exp2f(s[j][r] - m_r[r]);
          l_r[r] += e;
          int qr = fq * 4 + r;
          int key2 = (j * 16 + fr) * 2;
          *(u16*)((char*)Pw + qr * 128 + (key2 ^ ((qr & 7) << 4))) = f2bf(e);
        }
      }

      // O += P V
      __builtin_amdgcn_s_setprio(1);
#pragma unroll
      for (int kk = 0; kk < 2; ++kk) {
        int cbP = (kk * 64 + fq * 16) ^ ((fr & 7) << 4);
        bf16x8 pa = *(const bf16x8*)((const char*)Pw + fr * 128 + cbP);
#pragma unroll
        for (int fo = 0; fo < 4; ++fo)
          o[fo] = mfma16(pa, vfr_[fo][kk], o[fo]);
      }
      __builtin_amdgcn_s_setprio(0);
      cur ^= 1;
    }

    // final l reduce (once per item) + normalize + write ctx [B,S,D] bf16
#pragma unroll
    for (int msk = 1; msk < 16; msk <<= 1)
#pragma unroll
      for (int r = 0; r < 4; ++r) l_r[r] += __shfl_xor(l_r[r], msk);

#pragma unroll
    for (int fo = 0; fo < 4; ++fo) {
      int dh = fo * 16 + fr;
#pragma unroll
      for (int r = 0; r < 4; ++r) {
        int qg = qbase + fq * 4 + r;
        ctx[((size_t)b * Sz + qg) * Dz + h * DHz + dh] = f2bf(o[fo][r] / l_r[r]);
      }
    }
    __syncthreads();   // all waves done with LDS + s_item before next item
  }
}

// ---------------- launch ----------------
extern "C" void kernel_launch(void* const* d_in, const int* in_sizes, int n_in,
                              void* d_out, int out_size, void* d_ws, size_t ws_size,
                              hipStream_t stream) {
  const float* q  = (const float*)d_in[0];
  const float* k  = (const float*)d_in[1];
  const float* v  = (const float*)d_in[2];
  const float* Wq = (const float*)d_in[3];
  const float* bq = (const float*)d_in[4];
  const float* Wk = (const float*)d_in[5];
  const float* bk = (const float*)d_in[6];
  const float* Wv = (const float*)d_in[7];
  const float* bv = (const float*)d_in[8];
  const float* Wo = (const float*)d_in[9];
  const float* bo = (const float*)d_in[10];
  float* out = (float*)d_out;

  char* ws = (char*)d_ws;
  size_t off = 0;
  auto alloc = [&](size_t bytes) {
    void* p = ws + off;
    off += (bytes + 255) & ~(size_t)255;
    return p;
  };
  u16* qb  = (u16*)alloc((size_t)Mz * Dz * 2);
  u16* kb  = (u16*)alloc((size_t)Mz * Dz * 2);
  u16* vb  = (u16*)alloc((size_t)Mz * Dz * 2);
  u16* Wqt = (u16*)alloc((size_t)Dz * Dz * 2);
  u16* Wkt = (u16*)alloc((size_t)Dz * Dz * 2);
  u16* Wvt = (u16*)alloc((size_t)Dz * Dz * 2);
  u16* Wot = (u16*)alloc((size_t)Dz * Dz * 2);
  u16* Qh  = (u16*)alloc((size_t)Bz * Hz * Sz * DHz * 2);
  u16* Kh  = (u16*)alloc((size_t)Bz * Hz * Sz * DHz * 2);
  u16* Vtr = (u16*)alloc((size_t)Bz * Hz * DHz * Sz * 2);
  u16* ctx = (u16*)alloc((size_t)Mz * Dz * 2);
  int* cnt = (int*)alloc(256);

  int n8 = Mz * Dz / 8;
  int cblk = (n8 + 255) / 256;
  cvt3_kernel<<<dim3(cblk, 3), 256, 0, stream>>>(q, k, v, qb, kb, vb, n8, cnt);

  wtrans4_kernel<<<dim3(Dz / 32, Dz / 32, 4), 256, 0, stream>>>(
      Wq, Wk, Wv, Wo, Wqt, Wkt, Wvt, Wot);

  gemm_qkv<<<dim3(Mz / 128, Dz / 128, 3), 256, 0, stream>>>(
      qb, kb, vb, Wqt, Wkt, Wvt, bq, bk, bv, Qh, Kh, Vtr);

  attn_kernel<<<dim3(1024), 256, 0, stream>>>(Qh, Kh, Vtr, ctx, cnt);

  gemm_out_k<<<dim3(Mz / 128, Dz / 128), 256, 0, stream>>>(ctx, Wot, bo, out);
}

// Round 7
// 107.825 us; speedup vs baseline: 1.6760x; 1.2724x over previous
//
#include <hip/hip_runtime.h>
#include <hip/hip_bf16.h>
#include <stdint.h>

#define Bz 2
#define Sz 2048
#define Dz 768
#define Hz 12
#define DHz 64
#define Mz (Bz*Sz)   // 4096
#define NQT (Sz/64)  // 32 q-tiles per (b,h)

typedef __attribute__((ext_vector_type(4))) float f32x4;
typedef __attribute__((ext_vector_type(8))) short bf16x8;
typedef unsigned short u16;
typedef __attribute__((ext_vector_type(8))) unsigned short u16x8;

__device__ __forceinline__ u16 f2bf(float f) {
  union { float f; uint32_t u; } c; c.f = f;
  uint32_t u = c.u;
  return (u16)((u + 0x7fffu + ((u >> 16) & 1u)) >> 16);
}

#define GLL16(gsrc, ldst) \
  __builtin_amdgcn_global_load_lds((const __attribute__((address_space(1))) void*)(gsrc), \
                                   (__attribute__((address_space(3))) void*)(ldst), 16, 0, 0)

__device__ __forceinline__ f32x4 mfma16(bf16x8 a, bf16x8 b, f32x4 c) {
  return __builtin_amdgcn_mfma_f32_16x16x32_bf16(a, b, c, 0, 0, 0);
}

// ---------------- pre-pass: fp32 -> bf16 (q,k,v fused in one launch) ----------------
__global__ void cvt3_kernel(const float* __restrict__ qa, const float* __restrict__ ka,
                            const float* __restrict__ va,
                            u16* __restrict__ qo, u16* __restrict__ ko, u16* __restrict__ vo,
                            int n8) {
  int i = blockIdx.x * blockDim.x + threadIdx.x;
  if (i >= n8) return;
  int z = blockIdx.y;
  const float* src = (z == 0) ? qa : (z == 1) ? ka : va;
  u16* dst = (z == 0) ? qo : (z == 1) ? ko : vo;
  const float4* s4 = (const float4*)src;
  float4 a = s4[(size_t)i * 2];
  float4 b = s4[(size_t)i * 2 + 1];
  u16x8 o;
  o[0] = f2bf(a.x); o[1] = f2bf(a.y); o[2] = f2bf(a.z); o[3] = f2bf(a.w);
  o[4] = f2bf(b.x); o[5] = f2bf(b.y); o[6] = f2bf(b.z); o[7] = f2bf(b.w);
  *(u16x8*)(dst + (size_t)i * 8) = o;
}

// ---------------- pre-pass: W [K][N] fp32 -> Wt [N][K] bf16 (4 weights fused) ----------------
__global__ void wtrans4_kernel(const float* __restrict__ W0, const float* __restrict__ W1,
                               const float* __restrict__ W2, const float* __restrict__ W3,
                               u16* __restrict__ T0, u16* __restrict__ T1,
                               u16* __restrict__ T2, u16* __restrict__ T3) {
  __shared__ float tile[32][33];
  int z = blockIdx.z;
  const float* W = (z == 0) ? W0 : (z == 1) ? W1 : (z == 2) ? W2 : W3;
  u16* Wt = (z == 0) ? T0 : (z == 1) ? T1 : (z == 2) ? T2 : T3;
  int bx = blockIdx.x * 32, by = blockIdx.y * 32;
  int tx = threadIdx.x & 31, ty = threadIdx.x >> 5;   // 256 threads: ty 0..7
#pragma unroll
  for (int i = 0; i < 32; i += 8)
    tile[ty + i][tx] = W[(size_t)(by + ty + i) * Dz + bx + tx];
  __syncthreads();
#pragma unroll
  for (int i = 0; i < 32; i += 8)
    Wt[(size_t)(bx + ty + i) * Dz + by + tx] = f2bf(tile[tx][ty + i]);
}

// ---------------- GEMM core: C[M][N] = A[M][K] * Wt[N][K]^T + bias ----------------
// mode 0: bf16 out, layout [B,H,S,DH]   (Q, K projections)  (out = (acc+bias)*oscale)
// mode 1: bf16 out, layout [B,H,DH,S]   (V projection, transposed)
// mode 2: fp32 out, layout [M][N]       (final output projection)
__device__ __forceinline__ void gemm_core(
    const u16* __restrict__ A, const u16* __restrict__ Wt,
    const float* __restrict__ bias, void* __restrict__ out, int mode, float oscale,
    u16* As, u16* Bs)
{
  const int tid = threadIdx.x;
  const int wid = tid >> 6, lane = tid & 63;
  const int wm = wid >> 1, wn = wid & 1;
  const int m0 = blockIdx.x * 128, n0 = blockIdx.y * 128;
  const int fq = lane >> 4, fr = lane & 15;

  int aoff[2];
#pragma unroll
  for (int c = 0; c < 2; ++c) {
    int off  = (wid * 2 + c) * 1024 + lane * 16;
    int row  = off >> 6;
    int colb = (off & 63) ^ (((row >> 1) & 3) << 4);
    aoff[c]  = row * Dz + (colb >> 1);
  }

  int raddr[4], rbaddr[4];
#pragma unroll
  for (int f = 0; f < 4; ++f) {
    int rowA = wm * 64 + f * 16 + fr;
    raddr[f]  = rowA * 64 + ((fq * 16) ^ (((rowA >> 1) & 3) << 4));
    int rowB = wn * 64 + f * 16 + fr;
    rbaddr[f] = rowB * 64 + ((fq * 16) ^ (((rowB >> 1) & 3) << 4));
  }

  f32x4 acc[4][4];
  const f32x4 zero = {0.f, 0.f, 0.f, 0.f};
#pragma unroll
  for (int i = 0; i < 4; ++i)
#pragma unroll
    for (int j = 0; j < 4; ++j) acc[i][j] = zero;

  const u16* Abase = A + (size_t)m0 * Dz;
  const u16* Bbase = Wt + (size_t)n0 * Dz;

  for (int kt = 0; kt < Dz; kt += 32) {
#pragma unroll
    for (int c = 0; c < 2; ++c) {
      GLL16(Abase + kt + aoff[c], (char*)As + (wid * 2 + c) * 1024);
      GLL16(Bbase + kt + aoff[c], (char*)Bs + (wid * 2 + c) * 1024);
    }
    __syncthreads();
    bf16x8 af[4], bf[4];
#pragma unroll
    for (int f = 0; f < 4; ++f) {
      af[f] = *(const bf16x8*)((const char*)As + raddr[f]);
      bf[f] = *(const bf16x8*)((const char*)Bs + rbaddr[f]);
    }
    __builtin_amdgcn_s_setprio(1);
#pragma unroll
    for (int i = 0; i < 4; ++i)
#pragma unroll
      for (int j = 0; j < 4; ++j)
        acc[i][j] = mfma16(af[i], bf[j], acc[i][j]);
    __builtin_amdgcn_s_setprio(0);
    __syncthreads();
  }

  if (mode == 2) {
    float* O = (float*)out;
#pragma unroll
    for (int i = 0; i < 4; ++i) {
      int grow = m0 + wm * 64 + i * 16 + fq * 4;
#pragma unroll
      for (int j = 0; j < 4; ++j) {
        int gcol = n0 + wn * 64 + j * 16 + fr;
        float bv = bias[gcol];
#pragma unroll
        for (int r = 0; r < 4; ++r)
          O[(size_t)(grow + r) * Dz + gcol] = acc[i][j][r] + bv;
      }
    }
  } else {
    u16* O = (u16*)out;
#pragma unroll
    for (int i = 0; i < 4; ++i) {
      int grow = m0 + wm * 64 + i * 16 + fq * 4;
#pragma unroll
      for (int j = 0; j < 4; ++j) {
        int gcol = n0 + wn * 64 + j * 16 + fr;
        float bv = bias[gcol];
        int h = gcol >> 6, dh = gcol & 63;
#pragma unroll
        for (int r = 0; r < 4; ++r) {
          int t = grow + r;
          int b = t >> 11, s = t & 2047;
          float v = (acc[i][j][r] + bv) * oscale;
          if (mode == 0)
            O[((size_t)(b * Hz + h) * Sz + s) * DHz + dh] = f2bf(v);
          else
            O[((size_t)(b * Hz + h) * DHz + dh) * Sz + s] = f2bf(v);
        }
      }
    }
  }
}

// Q is pre-scaled by 1/sqrt(DH) * log2(e) so attention can use raw v_exp_f32 (exp2)
#define QSCALE 0.1803368801111404f   // 0.125 * 1.4426950408889634

__global__ __launch_bounds__(256, 2) void gemm_qkv(
    const u16* __restrict__ qb, const u16* __restrict__ kb, const u16* __restrict__ vb,
    const u16* __restrict__ Wqt, const u16* __restrict__ Wkt, const u16* __restrict__ Wvt,
    const float* __restrict__ bq, const float* __restrict__ bk, const float* __restrict__ bv,
    u16* __restrict__ Qh, u16* __restrict__ Kh, u16* __restrict__ Vt)
{
  __shared__ u16 As[128 * 32];
  __shared__ u16 Bs[128 * 32];
  const u16* A; const u16* W; const float* bias; u16* out; int mode; float osc;
  if (blockIdx.z == 0)      { A = qb; W = Wqt; bias = bq; out = Qh; mode = 0; osc = QSCALE; }
  else if (blockIdx.z == 1) { A = kb; W = Wkt; bias = bk; out = Kh; mode = 0; osc = 1.f; }
  else                      { A = vb; W = Wvt; bias = bv; out = Vt; mode = 1; osc = 1.f; }
  gemm_core(A, W, bias, out, mode, osc, As, Bs);
}

__global__ __launch_bounds__(256, 2) void gemm_out_k(
    const u16* __restrict__ ctx, const u16* __restrict__ Wot,
    const float* __restrict__ bo, float* __restrict__ out)
{
  __shared__ u16 As[128 * 32];
  __shared__ u16 Bs[128 * 32];
  gemm_core(ctx, Wot, bo, (void*)out, 2, 1.f, As, Bs);
}

// ---------------- flash attention, causal, PAIRED Q-TILES ----------------
// grid (B*H, NQT/2) = (24, 16). Block p handles q-tiles {p, 31-p}: stages k-tiles
// 0..31-p once and feeds BOTH q-tiles from the same LDS. Low tile active only for
// kt <= p, so total compute per block = 33 group-iters for every p (uniform), and
// heavy iterations carry two independent compute streams (2x ILP).
__device__ __forceinline__ void stage_kv(const u16* __restrict__ Kg, const u16* __restrict__ Vg,
                                         int kt, u16* Ks, u16* Vs, int wid, int lane) {
#pragma unroll
  for (int c = 0; c < 2; ++c) {
    int off  = (wid * 2 + c) * 1024 + lane * 16;
    int row  = off >> 7;                       // 128B rows (64 bf16)
    int colb = (off & 127) ^ ((row & 7) << 4); // XOR swizzle bits 4-6
    GLL16(Kg + ((size_t)(kt * 64 + row)) * DHz + (colb >> 1), (char*)Ks + (wid * 2 + c) * 1024);
    GLL16(Vg + (size_t)row * Sz + kt * 64 + (colb >> 1),      (char*)Vs + (wid * 2 + c) * 1024);
  }
}

// one q-tile group's work for one staged k-tile (all indices compile-time after inlining)
__device__ __forceinline__ void attn_group(
    const bf16x8* aq, const bf16x8 kfr[4][2], const bf16x8 vfr[4][2],
    f32x4* o, float* m_r, float* l_r, char* Pw,
    int qbase, int kt, bool diag, int fq, int fr)
{
  const f32x4 zero = {0.f, 0.f, 0.f, 0.f};
  f32x4 s[4];
#pragma unroll
  for (int j = 0; j < 4; ++j) s[j] = zero;
  __builtin_amdgcn_s_setprio(1);
#pragma unroll
  for (int j = 0; j < 4; ++j)
#pragma unroll
    for (int kk = 0; kk < 2; ++kk)
      s[j] = mfma16(aq[kk], kfr[j][kk], s[j]);
  __builtin_amdgcn_s_setprio(0);

  if (diag) {
#pragma unroll
    for (int j = 0; j < 4; ++j) {
      int keyg = kt * 64 + j * 16 + fr;
#pragma unroll
      for (int r = 0; r < 4; ++r)
        if (keyg > qbase + fq * 4 + r) s[j][r] = -1e30f;
    }
  }

  // per-lane partial row max (cross-lane reduce only when defer triggers)
  float mt[4];
#pragma unroll
  for (int r = 0; r < 4; ++r) mt[r] = s[0][r];
#pragma unroll
  for (int j = 1; j < 4; ++j)
#pragma unroll
    for (int r = 0; r < 4; ++r) mt[r] = fmaxf(mt[r], s[j][r]);

  int nd = 0;
#pragma unroll
  for (int r = 0; r < 4; ++r) nd |= (mt[r] > m_r[r] + 8.f) ? 1 : 0;
  if (__any(nd)) {
#pragma unroll
    for (int msk = 1; msk < 16; msk <<= 1)
#pragma unroll
      for (int r = 0; r < 4; ++r) mt[r] = fmaxf(mt[r], __shfl_xor(mt[r], msk));
#pragma unroll
    for (int r = 0; r < 4; ++r) {
      float mn = fmaxf(m_r[r], mt[r]);
      float alpha = __builtin_amdgcn_exp2f(m_r[r] - mn);
      m_r[r] = mn;
      l_r[r] *= alpha;
#pragma unroll
      for (int i = 0; i < 4; ++i) o[i][r] *= alpha;
    }
  }

  // P = exp2(S - m); per-lane partial l; write P to per-wave-per-group LDS
#pragma unroll
  for (int j = 0; j < 4; ++j) {
#pragma unroll
    for (int r = 0; r < 4; ++r) {
      float e = __builtin_amdgcn_exp2f(s[j][r] - m_r[r]);
      l_r[r] += e;
      int qr = fq * 4 + r;
      int key2 = (j * 16 + fr) * 2;
      *(u16*)(Pw + qr * 128 + (key2 ^ ((qr & 7) << 4))) = f2bf(e);
    }
  }

  // O += P V
  __builtin_amdgcn_s_setprio(1);
#pragma unroll
  for (int kk = 0; kk < 2; ++kk) {
    int cbP = (kk * 64 + fq * 16) ^ ((fr & 7) << 4);
    bf16x8 pa = *(const bf16x8*)(Pw + fr * 128 + cbP);
#pragma unroll
    for (int fo = 0; fo < 4; ++fo)
      o[fo] = mfma16(pa, vfr[fo][kk], o[fo]);
  }
  __builtin_amdgcn_s_setprio(0);
}

__global__ __launch_bounds__(256, 2) void attn_kernel(
    const u16* __restrict__ Qh, const u16* __restrict__ Kh,
    const u16* __restrict__ Vt, u16* __restrict__ ctx)
{
  __shared__ u16 Ks[2][64 * 64];        // 16 KB
  __shared__ u16 Vs[2][64 * 64];        // 16 KB
  __shared__ u16 Ps[4 * 2 * 16 * 64];   // 16 KB (per-wave, per-group P tile)
  const int tid = threadIdx.x, wid = tid >> 6, lane = tid & 63;
  const int fq = lane >> 4, fr = lane & 15;
  const int bh = blockIdx.x;
  const int p = blockIdx.y;              // pair index 0..15
  const int b = bh / Hz, h = bh % Hz;
  const int qb0 = p * 64 + wid * 16;                 // low q-tile rows
  const int qb1 = (NQT - 1 - p) * 64 + wid * 16;     // high q-tile rows
  const int nkt = NQT - p;               // staged k-tiles (covers high tile)
  const int nlo = p + 1;                 // low group active iterations

  const u16* Kg = Kh + (size_t)bh * Sz * DHz;
  const u16* Vg = Vt + (size_t)bh * DHz * Sz;
  const u16* Qg = Qh + (size_t)bh * Sz * DHz;

  // Q fragments for both groups (pre-scaled by QSCALE at projection)
  bf16x8 aq[2][2];
#pragma unroll
  for (int kk = 0; kk < 2; ++kk) {
    aq[0][kk] = *(const bf16x8*)(Qg + (qb0 + fr) * DHz + kk * 32 + fq * 8);
    aq[1][kk] = *(const bf16x8*)(Qg + (qb1 + fr) * DHz + kk * 32 + fq * 8);
  }

  const f32x4 zero = {0.f, 0.f, 0.f, 0.f};
  f32x4 o[2][4];
#pragma unroll
  for (int g = 0; g < 2; ++g)
#pragma unroll
    for (int i = 0; i < 4; ++i) o[g][i] = zero;
  float m_r[2][4], l_r[2][4];
#pragma unroll
  for (int g = 0; g < 2; ++g)
#pragma unroll
    for (int r = 0; r < 4; ++r) { m_r[g][r] = -1e30f; l_r[g][r] = 0.f; }

  char* Pw0 = (char*)(Ps + (wid * 2 + 0) * 16 * 64);
  char* Pw1 = (char*)(Ps + (wid * 2 + 1) * 16 * 64);

  stage_kv(Kg, Vg, 0, Ks[0], Vs[0], wid, lane);
  int cur = 0;

  for (int kt = 0; kt < nkt; ++kt) {
    __syncthreads();   // buf[cur] staging drained; prev tile's LDS reads complete
    if (kt + 1 < nkt)
      stage_kv(Kg, Vg, kt + 1, Ks[cur ^ 1], Vs[cur ^ 1], wid, lane);

    const char* Kb = (const char*)Ks[cur];
    const char* Vb = (const char*)Vs[cur];

    // shared K fragments
    bf16x8 kfr[4][2];
#pragma unroll
    for (int j = 0; j < 4; ++j) {
      int rowK = j * 16 + fr;
#pragma unroll
      for (int kk = 0; kk < 2; ++kk)
        kfr[j][kk] = *(const bf16x8*)(Kb + rowK * 128 + ((kk * 64 + fq * 16) ^ ((rowK & 7) << 4)));
    }
    // shared V fragments
    bf16x8 vfr[4][2];
#pragma unroll
    for (int fo = 0; fo < 4; ++fo) {
      int rowV = fo * 16 + fr;
#pragma unroll
      for (int kk = 0; kk < 2; ++kk)
        vfr[fo][kk] = *(const bf16x8*)(Vb + rowV * 128 + ((kk * 64 + fq * 16) ^ ((rowV & 7) << 4)));
    }

    if (kt < nlo)
      attn_group(aq[0], kfr, vfr, o[0], m_r[0], l_r[0], Pw0, qb0, kt, kt == nlo - 1, fq, fr);
    attn_group(aq[1], kfr, vfr, o[1], m_r[1], l_r[1], Pw1, qb1, kt, kt == nkt - 1, fq, fr);

    cur ^= 1;
  }

  // final l reduce (once) + normalize + write ctx [B,S,D] bf16
#pragma unroll
  for (int msk = 1; msk < 16; msk <<= 1)
#pragma unroll
    for (int g = 0; g < 2; ++g)
#pragma unroll
      for (int r = 0; r < 4; ++r) l_r[g][r] += __shfl_xor(l_r[g][r], msk);

#pragma unroll
  for (int g = 0; g < 2; ++g) {
    int qb = (g == 0) ? qb0 : qb1;
#pragma unroll
    for (int fo = 0; fo < 4; ++fo) {
      int dh = fo * 16 + fr;
#pragma unroll
      for (int r = 0; r < 4; ++r) {
        int qg = qb + fq * 4 + r;
        ctx[((size_t)b * Sz + qg) * Dz + h * DHz + dh] = f2bf(o[g][fo][r] / l_r[g][r]);
      }
    }
  }
}

// ---------------- launch ----------------
extern "C" void kernel_launch(void* const* d_in, const int* in_sizes, int n_in,
                              void* d_out, int out_size, void* d_ws, size_t ws_size,
                              hipStream_t stream) {
  const float* q  = (const float*)d_in[0];
  const float* k  = (const float*)d_in[1];
  const float* v  = (const float*)d_in[2];
  const float* Wq = (const float*)d_in[3];
  const float* bq = (const float*)d_in[4];
  const float* Wk = (const float*)d_in[5];
  const float* bk = (const float*)d_in[6];
  const float* Wv = (const float*)d_in[7];
  const float* bv = (const float*)d_in[8];
  const float* Wo = (const float*)d_in[9];
  const float* bo = (const float*)d_in[10];
  float* out = (float*)d_out;

  char* ws = (char*)d_ws;
  size_t off = 0;
  auto alloc = [&](size_t bytes) {
    void* p = ws + off;
    off += (bytes + 255) & ~(size_t)255;
    return p;
  };
  u16* qb  = (u16*)alloc((size_t)Mz * Dz * 2);
  u16* kb  = (u16*)alloc((size_t)Mz * Dz * 2);
  u16* vb  = (u16*)alloc((size_t)Mz * Dz * 2);
  u16* Wqt = (u16*)alloc((size_t)Dz * Dz * 2);
  u16* Wkt = (u16*)alloc((size_t)Dz * Dz * 2);
  u16* Wvt = (u16*)alloc((size_t)Dz * Dz * 2);
  u16* Wot = (u16*)alloc((size_t)Dz * Dz * 2);
  u16* Qh  = (u16*)alloc((size_t)Bz * Hz * Sz * DHz * 2);
  u16* Kh  = (u16*)alloc((size_t)Bz * Hz * Sz * DHz * 2);
  u16* Vtr = (u16*)alloc((size_t)Bz * Hz * DHz * Sz * 2);
  u16* ctx = (u16*)alloc((size_t)Mz * Dz * 2);

  int n8 = Mz * Dz / 8;
  int cblk = (n8 + 255) / 256;
  cvt3_kernel<<<dim3(cblk, 3), 256, 0, stream>>>(q, k, v, qb, kb, vb, n8);

  wtrans4_kernel<<<dim3(Dz / 32, Dz / 32, 4), 256, 0, stream>>>(
      Wq, Wk, Wv, Wo, Wqt, Wkt, Wvt, Wot);

  gemm_qkv<<<dim3(Mz / 128, Dz / 128, 3), 256, 0, stream>>>(
      qb, kb, vb, Wqt, Wkt, Wvt, bq, bk, bv, Qh, Kh, Vtr);

  attn_kernel<<<dim3(Bz * Hz, NQT / 2), 256, 0, stream>>>(Qh, Kh, Vtr, ctx);

  gemm_out_k<<<dim3(Mz / 128, Dz / 128), 256, 0, stream>>>(ctx, Wot, bo, out);
}

// Round 8
// 106.048 us; speedup vs baseline: 1.7041x; 1.0167x over previous
//
#include <hip/hip_runtime.h>
#include <hip/hip_bf16.h>
#include <stdint.h>

#define Bz 2
#define Sz 2048
#define Dz 768
#define Hz 12
#define DHz 64
#define Mz (Bz*Sz)    // 4096
#define NQT2 64       // 32-row q-tiles per (b,h)

typedef __attribute__((ext_vector_type(4))) float f32x4;
typedef __attribute__((ext_vector_type(8))) short bf16x8;
typedef unsigned short u16;
typedef __attribute__((ext_vector_type(8))) unsigned short u16x8;

__device__ __forceinline__ u16 f2bf(float f) {
  union { float f; uint32_t u; } c; c.f = f;
  uint32_t u = c.u;
  return (u16)((u + 0x7fffu + ((u >> 16) & 1u)) >> 16);
}

#define GLL16(gsrc, ldst) \
  __builtin_amdgcn_global_load_lds((const __attribute__((address_space(1))) void*)(gsrc), \
                                   (__attribute__((address_space(3))) void*)(ldst), 16, 0, 0)

__device__ __forceinline__ f32x4 mfma16(bf16x8 a, bf16x8 b, f32x4 c) {
  return __builtin_amdgcn_mfma_f32_16x16x32_bf16(a, b, c, 0, 0, 0);
}

// ---------------- pre-pass: fp32 -> bf16 (q,k,v fused in one launch) ----------------
__global__ void cvt3_kernel(const float* __restrict__ qa, const float* __restrict__ ka,
                            const float* __restrict__ va,
                            u16* __restrict__ qo, u16* __restrict__ ko, u16* __restrict__ vo,
                            int n8) {
  int i = blockIdx.x * blockDim.x + threadIdx.x;
  if (i >= n8) return;
  int z = blockIdx.y;
  const float* src = (z == 0) ? qa : (z == 1) ? ka : va;
  u16* dst = (z == 0) ? qo : (z == 1) ? ko : vo;
  const float4* s4 = (const float4*)src;
  float4 a = s4[(size_t)i * 2];
  float4 b = s4[(size_t)i * 2 + 1];
  u16x8 o;
  o[0] = f2bf(a.x); o[1] = f2bf(a.y); o[2] = f2bf(a.z); o[3] = f2bf(a.w);
  o[4] = f2bf(b.x); o[5] = f2bf(b.y); o[6] = f2bf(b.z); o[7] = f2bf(b.w);
  *(u16x8*)(dst + (size_t)i * 8) = o;
}

// ---------------- pre-pass: W [K][N] fp32 -> Wt [N][K] bf16 (4 weights fused) ----------------
__global__ void wtrans4_kernel(const float* __restrict__ W0, const float* __restrict__ W1,
                               const float* __restrict__ W2, const float* __restrict__ W3,
                               u16* __restrict__ T0, u16* __restrict__ T1,
                               u16* __restrict__ T2, u16* __restrict__ T3) {
  __shared__ float tile[32][33];
  int z = blockIdx.z;
  const float* W = (z == 0) ? W0 : (z == 1) ? W1 : (z == 2) ? W2 : W3;
  u16* Wt = (z == 0) ? T0 : (z == 1) ? T1 : (z == 2) ? T2 : T3;
  int bx = blockIdx.x * 32, by = blockIdx.y * 32;
  int tx = threadIdx.x & 31, ty = threadIdx.x >> 5;   // 256 threads: ty 0..7
#pragma unroll
  for (int i = 0; i < 32; i += 8)
    tile[ty + i][tx] = W[(size_t)(by + ty + i) * Dz + bx + tx];
  __syncthreads();
#pragma unroll
  for (int i = 0; i < 32; i += 8)
    Wt[(size_t)(bx + ty + i) * Dz + by + tx] = f2bf(tile[tx][ty + i]);
}

// ---------------- GEMM core: C[M][N] = A[M][K] * Wt[N][K]^T + bias ----------------
// mode 0: bf16 out, layout [B,H,S,DH]   (Q, K projections)  (out = (acc+bias)*oscale)
// mode 1: bf16 out, layout [B,H,DH,S]   (V projection, transposed)
// mode 2: fp32 out, layout [M][N]       (final output projection)
__device__ __forceinline__ void gemm_core(
    const u16* __restrict__ A, const u16* __restrict__ Wt,
    const float* __restrict__ bias, void* __restrict__ out, int mode, float oscale,
    u16* As, u16* Bs)
{
  const int tid = threadIdx.x;
  const int wid = tid >> 6, lane = tid & 63;
  const int wm = wid >> 1, wn = wid & 1;
  const int m0 = blockIdx.x * 128, n0 = blockIdx.y * 128;
  const int fq = lane >> 4, fr = lane & 15;

  int aoff[2];
#pragma unroll
  for (int c = 0; c < 2; ++c) {
    int off  = (wid * 2 + c) * 1024 + lane * 16;
    int row  = off >> 6;
    int colb = (off & 63) ^ (((row >> 1) & 3) << 4);
    aoff[c]  = row * Dz + (colb >> 1);
  }

  int raddr[4], rbaddr[4];
#pragma unroll
  for (int f = 0; f < 4; ++f) {
    int rowA = wm * 64 + f * 16 + fr;
    raddr[f]  = rowA * 64 + ((fq * 16) ^ (((rowA >> 1) & 3) << 4));
    int rowB = wn * 64 + f * 16 + fr;
    rbaddr[f] = rowB * 64 + ((fq * 16) ^ (((rowB >> 1) & 3) << 4));
  }

  f32x4 acc[4][4];
  const f32x4 zero = {0.f, 0.f, 0.f, 0.f};
#pragma unroll
  for (int i = 0; i < 4; ++i)
#pragma unroll
    for (int j = 0; j < 4; ++j) acc[i][j] = zero;

  const u16* Abase = A + (size_t)m0 * Dz;
  const u16* Bbase = Wt + (size_t)n0 * Dz;

  for (int kt = 0; kt < Dz; kt += 32) {
#pragma unroll
    for (int c = 0; c < 2; ++c) {
      GLL16(Abase + kt + aoff[c], (char*)As + (wid * 2 + c) * 1024);
      GLL16(Bbase + kt + aoff[c], (char*)Bs + (wid * 2 + c) * 1024);
    }
    __syncthreads();
    bf16x8 af[4], bf[4];
#pragma unroll
    for (int f = 0; f < 4; ++f) {
      af[f] = *(const bf16x8*)((const char*)As + raddr[f]);
      bf[f] = *(const bf16x8*)((const char*)Bs + rbaddr[f]);
    }
    __builtin_amdgcn_s_setprio(1);
#pragma unroll
    for (int i = 0; i < 4; ++i)
#pragma unroll
      for (int j = 0; j < 4; ++j)
        acc[i][j] = mfma16(af[i], bf[j], acc[i][j]);
    __builtin_amdgcn_s_setprio(0);
    __syncthreads();
  }

  if (mode == 2) {
    float* O = (float*)out;
#pragma unroll
    for (int i = 0; i < 4; ++i) {
      int grow = m0 + wm * 64 + i * 16 + fq * 4;
#pragma unroll
      for (int j = 0; j < 4; ++j) {
        int gcol = n0 + wn * 64 + j * 16 + fr;
        float bv = bias[gcol];
#pragma unroll
        for (int r = 0; r < 4; ++r)
          O[(size_t)(grow + r) * Dz + gcol] = acc[i][j][r] + bv;
      }
    }
  } else {
    u16* O = (u16*)out;
#pragma unroll
    for (int i = 0; i < 4; ++i) {
      int grow = m0 + wm * 64 + i * 16 + fq * 4;
#pragma unroll
      for (int j = 0; j < 4; ++j) {
        int gcol = n0 + wn * 64 + j * 16 + fr;
        float bv = bias[gcol];
        int h = gcol >> 6, dh = gcol & 63;
#pragma unroll
        for (int r = 0; r < 4; ++r) {
          int t = grow + r;
          int b = t >> 11, s = t & 2047;
          float v = (acc[i][j][r] + bv) * oscale;
          if (mode == 0)
            O[((size_t)(b * Hz + h) * Sz + s) * DHz + dh] = f2bf(v);
          else
            O[((size_t)(b * Hz + h) * DHz + dh) * Sz + s] = f2bf(v);
        }
      }
    }
  }
}

// Q is pre-scaled by 1/sqrt(DH) * log2(e) so attention can use raw v_exp_f32 (exp2)
#define QSCALE 0.1803368801111404f   // 0.125 * 1.4426950408889634

__global__ __launch_bounds__(256, 2) void gemm_qkv(
    const u16* __restrict__ qb, const u16* __restrict__ kb, const u16* __restrict__ vb,
    const u16* __restrict__ Wqt, const u16* __restrict__ Wkt, const u16* __restrict__ Wvt,
    const float* __restrict__ bq, const float* __restrict__ bk, const float* __restrict__ bv,
    u16* __restrict__ Qh, u16* __restrict__ Kh, u16* __restrict__ Vt)
{
  __shared__ u16 As[128 * 32];
  __shared__ u16 Bs[128 * 32];
  const u16* A; const u16* W; const float* bias; u16* out; int mode; float osc;
  if (blockIdx.z == 0)      { A = qb; W = Wqt; bias = bq; out = Qh; mode = 0; osc = QSCALE; }
  else if (blockIdx.z == 1) { A = kb; W = Wkt; bias = bk; out = Kh; mode = 0; osc = 1.f; }
  else                      { A = vb; W = Wvt; bias = bv; out = Vt; mode = 1; osc = 1.f; }
  gemm_core(A, W, bias, out, mode, osc, As, Bs);
}

__global__ __launch_bounds__(256, 2) void gemm_out_k(
    const u16* __restrict__ ctx, const u16* __restrict__ Wot,
    const float* __restrict__ bo, float* __restrict__ out)
{
  __shared__ u16 As[128 * 32];
  __shared__ u16 Bs[128 * 32];
  gemm_core(ctx, Wot, bo, (void*)out, 2, 1.f, As, Bs);
}

// ---------------- flash attention, causal, PAIRED 32-ROW Q-TILES ----------------
// grid (B*H, NQT2/2) = (24, 32) = 768 blocks of 128 threads (2 waves).
// Block p handles q-tiles {p, 63-p} (32 rows each): stages k-tiles 0..nkt-1 once,
// feeds both tiles from the same LDS (low tile active only while kt < nlo).
// Wave w owns rows [w*16..w*16+15] of BOTH tiles. Uniform compute per block
// (~32.5 group-iters), 36KB LDS -> up to 4 blocks/CU co-resident.
__device__ __forceinline__ void stage_kv(const u16* __restrict__ Kg, const u16* __restrict__ Vg,
                                         int kt, u16* Ks, u16* Vs, int wid, int lane) {
#pragma unroll
  for (int c = 0; c < 4; ++c) {
    int off  = (wid * 4 + c) * 1024 + lane * 16;
    int row  = off >> 7;                       // 128B rows (64 bf16)
    int colb = (off & 127) ^ ((row & 7) << 4); // XOR swizzle bits 4-6
    GLL16(Kg + ((size_t)(kt * 64 + row)) * DHz + (colb >> 1), (char*)Ks + (wid * 4 + c) * 1024);
    GLL16(Vg + (size_t)row * Sz + kt * 64 + (colb >> 1),      (char*)Vs + (wid * 4 + c) * 1024);
  }
}

// one 16-row group's work for one staged k-tile
__device__ __forceinline__ void attn_group(
    const bf16x8* aq, const bf16x8 kfr[4][2], const bf16x8 vfr[4][2],
    f32x4* o, float* m_r, float* l_r, char* Pw,
    int qbase, int kt, bool diag, int fq, int fr)
{
  const f32x4 zero = {0.f, 0.f, 0.f, 0.f};
  f32x4 s[4];
#pragma unroll
  for (int j = 0; j < 4; ++j) s[j] = zero;
  __builtin_amdgcn_s_setprio(1);
#pragma unroll
  for (int j = 0; j < 4; ++j)
#pragma unroll
    for (int kk = 0; kk < 2; ++kk)
      s[j] = mfma16(aq[kk], kfr[j][kk], s[j]);
  __builtin_amdgcn_s_setprio(0);

  if (diag) {
#pragma unroll
    for (int j = 0; j < 4; ++j) {
      int keyg = kt * 64 + j * 16 + fr;
#pragma unroll
      for (int r = 0; r < 4; ++r)
        if (keyg > qbase + fq * 4 + r) s[j][r] = -1e30f;
    }
  }

  // per-lane partial row max (cross-lane reduce only when defer triggers)
  float mt[4];
#pragma unroll
  for (int r = 0; r < 4; ++r) mt[r] = s[0][r];
#pragma unroll
  for (int j = 1; j < 4; ++j)
#pragma unroll
    for (int r = 0; r < 4; ++r) mt[r] = fmaxf(mt[r], s[j][r]);

  int nd = 0;
#pragma unroll
  for (int r = 0; r < 4; ++r) nd |= (mt[r] > m_r[r] + 8.f) ? 1 : 0;
  if (__any(nd)) {
#pragma unroll
    for (int msk = 1; msk < 16; msk <<= 1)
#pragma unroll
      for (int r = 0; r < 4; ++r) mt[r] = fmaxf(mt[r], __shfl_xor(mt[r], msk));
#pragma unroll
    for (int r = 0; r < 4; ++r) {
      float mn = fmaxf(m_r[r], mt[r]);
      float alpha = __builtin_amdgcn_exp2f(m_r[r] - mn);
      m_r[r] = mn;
      l_r[r] *= alpha;
#pragma unroll
      for (int i = 0; i < 4; ++i) o[i][r] *= alpha;
    }
  }

  // P = exp2(S - m); per-lane partial l; write P to per-wave LDS (swizzled)
#pragma unroll
  for (int j = 0; j < 4; ++j) {
#pragma unroll
    for (int r = 0; r < 4; ++r) {
      float e = __builtin_amdgcn_exp2f(s[j][r] - m_r[r]);
      l_r[r] += e;
      int qr = fq * 4 + r;
      int key2 = (j * 16 + fr) * 2;
      *(u16*)(Pw + qr * 128 + (key2 ^ ((qr & 7) << 4))) = f2bf(e);
    }
  }

  // O += P V
  __builtin_amdgcn_s_setprio(1);
#pragma unroll
  for (int kk = 0; kk < 2; ++kk) {
    int cbP = (kk * 64 + fq * 16) ^ ((fr & 7) << 4);
    bf16x8 pa = *(const bf16x8*)(Pw + fr * 128 + cbP);
#pragma unroll
    for (int fo = 0; fo < 4; ++fo)
      o[fo] = mfma16(pa, vfr[fo][kk], o[fo]);
  }
  __builtin_amdgcn_s_setprio(0);
}

__global__ __launch_bounds__(128, 2) void attn_kernel(
    const u16* __restrict__ Qh, const u16* __restrict__ Kh,
    const u16* __restrict__ Vt, u16* __restrict__ ctx)
{
  __shared__ u16 Ks[2][64 * 64];     // 16 KB
  __shared__ u16 Vs[2][64 * 64];     // 16 KB
  __shared__ u16 Ps[2 * 16 * 64];    //  4 KB (per-wave P, reused by both groups)
  const int tid = threadIdx.x, wid = tid >> 6, lane = tid & 63;
  const int fq = lane >> 4, fr = lane & 15;
  const int bh = blockIdx.x;
  const int p = blockIdx.y;            // pair index 0..31 (heaviest staging first)
  const int b = bh / Hz, h = bh % Hz;
  const int qb0 = p * 32 + wid * 16;                 // low q-tile rows (this wave)
  const int qb1 = (NQT2 - 1 - p) * 32 + wid * 16;    // high q-tile rows
  const int nkt = ((NQT2 - p) * 32 + 63) / 64;       // staged k-tiles (covers high)
  const int nlo = ((p + 1) * 32 + 63) / 64;          // low group active iterations

  const u16* Kg = Kh + (size_t)bh * Sz * DHz;
  const u16* Vg = Vt + (size_t)bh * DHz * Sz;
  const u16* Qg = Qh + (size_t)bh * Sz * DHz;

  bf16x8 aq[2][2];
#pragma unroll
  for (int kk = 0; kk < 2; ++kk) {
    aq[0][kk] = *(const bf16x8*)(Qg + (qb0 + fr) * DHz + kk * 32 + fq * 8);
    aq[1][kk] = *(const bf16x8*)(Qg + (qb1 + fr) * DHz + kk * 32 + fq * 8);
  }

  const f32x4 zero = {0.f, 0.f, 0.f, 0.f};
  f32x4 o[2][4];
#pragma unroll
  for (int g = 0; g < 2; ++g)
#pragma unroll
    for (int i = 0; i < 4; ++i) o[g][i] = zero;
  float m_r[2][4], l_r[2][4];
#pragma unroll
  for (int g = 0; g < 2; ++g)
#pragma unroll
    for (int r = 0; r < 4; ++r) { m_r[g][r] = -1e30f; l_r[g][r] = 0.f; }

  char* Pw = (char*)(Ps + wid * 16 * 64);

  stage_kv(Kg, Vg, 0, Ks[0], Vs[0], wid, lane);
  int cur = 0;

  for (int kt = 0; kt < nkt; ++kt) {
    __syncthreads();   // buf[cur] staging drained; prev tile's LDS reads complete
    if (kt + 1 < nkt)
      stage_kv(Kg, Vg, kt + 1, Ks[cur ^ 1], Vs[cur ^ 1], wid, lane);

    const char* Kb = (const char*)Ks[cur];
    const char* Vb = (const char*)Vs[cur];

    // shared K fragments
    bf16x8 kfr[4][2];
#pragma unroll
    for (int j = 0; j < 4; ++j) {
      int rowK = j * 16 + fr;
#pragma unroll
      for (int kk = 0; kk < 2; ++kk)
        kfr[j][kk] = *(const bf16x8*)(Kb + rowK * 128 + ((kk * 64 + fq * 16) ^ ((rowK & 7) << 4)));
    }
    // shared V fragments
    bf16x8 vfr[4][2];
#pragma unroll
    for (int fo = 0; fo < 4; ++fo) {
      int rowV = fo * 16 + fr;
#pragma unroll
      for (int kk = 0; kk < 2; ++kk)
        vfr[fo][kk] = *(const bf16x8*)(Vb + rowV * 128 + ((kk * 64 + fq * 16) ^ ((rowV & 7) << 4)));
    }

    if (kt < nlo)
      attn_group(aq[0], kfr, vfr, o[0], m_r[0], l_r[0], Pw, qb0, kt, kt == nlo - 1, fq, fr);
    attn_group(aq[1], kfr, vfr, o[1], m_r[1], l_r[1], Pw, qb1, kt, kt == nkt - 1, fq, fr);

    cur ^= 1;
  }

  // final l reduce (once) + normalize + write ctx [B,S,D] bf16
#pragma unroll
  for (int msk = 1; msk < 16; msk <<= 1)
#pragma unroll
    for (int g = 0; g < 2; ++g)
#pragma unroll
      for (int r = 0; r < 4; ++r) l_r[g][r] += __shfl_xor(l_r[g][r], msk);

#pragma unroll
  for (int g = 0; g < 2; ++g) {
    int qb = (g == 0) ? qb0 : qb1;
#pragma unroll
    for (int fo = 0; fo < 4; ++fo) {
      int dh = fo * 16 + fr;
#pragma unroll
      for (int r = 0; r < 4; ++r) {
        int qg = qb + fq * 4 + r;
        ctx[((size_t)b * Sz + qg) * Dz + h * DHz + dh] = f2bf(o[g][fo][r] / l_r[g][r]);
      }
    }
  }
}

// ---------------- launch ----------------
extern "C" void kernel_launch(void* const* d_in, const int* in_sizes, int n_in,
                              void* d_out, int out_size, void* d_ws, size_t ws_size,
                              hipStream_t stream) {
  const float* q  = (const float*)d_in[0];
  const float* k  = (const float*)d_in[1];
  const float* v  = (const float*)d_in[2];
  const float* Wq = (const float*)d_in[3];
  const float* bq = (const float*)d_in[4];
  const float* Wk = (const float*)d_in[5];
  const float* bk = (const float*)d_in[6];
  const float* Wv = (const float*)d_in[7];
  const float* bv = (const float*)d_in[8];
  const float* Wo = (const float*)d_in[9];
  const float* bo = (const float*)d_in[10];
  float* out = (float*)d_out;

  char* ws = (char*)d_ws;
  size_t off = 0;
  auto alloc = [&](size_t bytes) {
    void* p = ws + off;
    off += (bytes + 255) & ~(size_t)255;
    return p;
  };
  u16* qb  = (u16*)alloc((size_t)Mz * Dz * 2);
  u16* kb  = (u16*)alloc((size_t)Mz * Dz * 2);
  u16* vb  = (u16*)alloc((size_t)Mz * Dz * 2);
  u16* Wqt = (u16*)alloc((size_t)Dz * Dz * 2);
  u16* Wkt = (u16*)alloc((size_t)Dz * Dz * 2);
  u16* Wvt = (u16*)alloc((size_t)Dz * Dz * 2);
  u16* Wot = (u16*)alloc((size_t)Dz * Dz * 2);
  u16* Qh  = (u16*)alloc((size_t)Bz * Hz * Sz * DHz * 2);
  u16* Kh  = (u16*)alloc((size_t)Bz * Hz * Sz * DHz * 2);
  u16* Vtr = (u16*)alloc((size_t)Bz * Hz * DHz * Sz * 2);
  u16* ctx = (u16*)alloc((size_t)Mz * Dz * 2);

  int n8 = Mz * Dz / 8;
  int cblk = (n8 + 255) / 256;
  cvt3_kernel<<<dim3(cblk, 3), 256, 0, stream>>>(q, k, v, qb, kb, vb, n8);

  wtrans4_kernel<<<dim3(Dz / 32, Dz / 32, 4), 256, 0, stream>>>(
      Wq, Wk, Wv, Wo, Wqt, Wkt, Wvt, Wot);

  gemm_qkv<<<dim3(Mz / 128, Dz / 128, 3), 256, 0, stream>>>(
      qb, kb, vb, Wqt, Wkt, Wvt, bq, bk, bv, Qh, Kh, Vtr);

  attn_kernel<<<dim3(Bz * Hz, NQT2 / 2), 128, 0, stream>>>(Qh, Kh, Vtr, ctx);

  gemm_out_k<<<dim3(Mz / 128, Dz / 128), 256, 0, stream>>>(ctx, Wot, bo, out);
}

// Round 10
// 104.289 us; speedup vs baseline: 1.7329x; 1.0169x over previous
//
#include <hip/hip_runtime.h>
#include <hip/hip_bf16.h>
#include <stdint.h>

#define Bz 2
#define Sz 2048
#define Dz 768
#define Hz 12
#define DHz 64
#define Mz (Bz*Sz)    // 4096
#define NQT2 64       // 32-row q-tiles per (b,h)

typedef __attribute__((ext_vector_type(4))) float f32x4;
typedef __attribute__((ext_vector_type(8))) short bf16x8;
typedef unsigned short u16;
typedef __attribute__((ext_vector_type(8))) unsigned short u16x8;

__device__ __forceinline__ u16 f2bf(float f) {
  union { float f; uint32_t u; } c; c.f = f;
  uint32_t u = c.u;
  return (u16)((u + 0x7fffu + ((u >> 16) & 1u)) >> 16);
}

#define GLL16(gsrc, ldst) \
  __builtin_amdgcn_global_load_lds((const __attribute__((address_space(1))) void*)(gsrc), \
                                   (__attribute__((address_space(3))) void*)(ldst), 16, 0, 0)

__device__ __forceinline__ f32x4 mfma16(bf16x8 a, bf16x8 b, f32x4 c) {
  return __builtin_amdgcn_mfma_f32_16x16x32_bf16(a, b, c, 0, 0, 0);
}

// ---------------- pre-pass: fp32 -> bf16 (q,k,v fused in one launch) ----------------
__global__ void cvt3_kernel(const float* __restrict__ qa, const float* __restrict__ ka,
                            const float* __restrict__ va,
                            u16* __restrict__ qo, u16* __restrict__ ko, u16* __restrict__ vo,
                            int n8) {
  int i = blockIdx.x * blockDim.x + threadIdx.x;
  if (i >= n8) return;
  int z = blockIdx.y;
  const float* src = (z == 0) ? qa : (z == 1) ? ka : va;
  u16* dst = (z == 0) ? qo : (z == 1) ? ko : vo;
  const float4* s4 = (const float4*)src;
  float4 a = s4[(size_t)i * 2];
  float4 b = s4[(size_t)i * 2 + 1];
  u16x8 o;
  o[0] = f2bf(a.x); o[1] = f2bf(a.y); o[2] = f2bf(a.z); o[3] = f2bf(a.w);
  o[4] = f2bf(b.x); o[5] = f2bf(b.y); o[6] = f2bf(b.z); o[7] = f2bf(b.w);
  *(u16x8*)(dst + (size_t)i * 8) = o;
}

// ---------------- pre-pass: W [K][N] fp32 -> Wt [N][K] bf16 (4 weights fused) ----------------
__global__ void wtrans4_kernel(const float* __restrict__ W0, const float* __restrict__ W1,
                               const float* __restrict__ W2, const float* __restrict__ W3,
                               u16* __restrict__ T0, u16* __restrict__ T1,
                               u16* __restrict__ T2, u16* __restrict__ T3) {
  __shared__ float tile[32][33];
  int z = blockIdx.z;
  const float* W = (z == 0) ? W0 : (z == 1) ? W1 : (z == 2) ? W2 : W3;
  u16* Wt = (z == 0) ? T0 : (z == 1) ? T1 : (z == 2) ? T2 : T3;
  int bx = blockIdx.x * 32, by = blockIdx.y * 32;
  int tx = threadIdx.x & 31, ty = threadIdx.x >> 5;   // 256 threads: ty 0..7
#pragma unroll
  for (int i = 0; i < 32; i += 8)
    tile[ty + i][tx] = W[(size_t)(by + ty + i) * Dz + bx + tx];
  __syncthreads();
#pragma unroll
  for (int i = 0; i < 32; i += 8)
    Wt[(size_t)(bx + ty + i) * Dz + by + tx] = f2bf(tile[tx][ty + i]);
}

// ---------------- GEMM core: C[M][N] = A[M][K] * Wt[N][K]^T + bias ----------------
// TRIPLE-buffered, ONE raw barrier per K-step, counted vmcnt (T4). Triple buffer
// makes the pre-barrier prefetch race-free: within any barrier window, reads
// touch only buf[kt%3] while in-flight writes land in buf[(kt+1)%3]/buf[(kt+2)%3].
// mode 0: bf16 out, layout [B,H,S,DH]   (Q, K projections)  (out = (acc+bias)*oscale)
// mode 1: bf16 out, layout [B,H,DH,S]   (V projection, transposed)
// mode 2: fp32 out, layout [M][N]       (final output projection)
__device__ __forceinline__ void gemm_core(
    const u16* __restrict__ A, const u16* __restrict__ Wt,
    const float* __restrict__ bias, void* __restrict__ out, int mode, float oscale,
    u16 (*As)[128 * 32], u16 (*Bs)[128 * 32])
{
  const int tid = threadIdx.x;
  const int wid = tid >> 6, lane = tid & 63;
  const int wm = wid >> 1, wn = wid & 1;
  const int m0 = blockIdx.x * 128, n0 = blockIdx.y * 128;
  const int fq = lane >> 4, fr = lane & 15;

  int aoff[2];
#pragma unroll
  for (int c = 0; c < 2; ++c) {
    int off  = (wid * 2 + c) * 1024 + lane * 16;
    int row  = off >> 6;
    int colb = (off & 63) ^ (((row >> 1) & 3) << 4);
    aoff[c]  = row * Dz + (colb >> 1);
  }

  int raddr[4], rbaddr[4];
#pragma unroll
  for (int f = 0; f < 4; ++f) {
    int rowA = wm * 64 + f * 16 + fr;
    raddr[f]  = rowA * 64 + ((fq * 16) ^ (((rowA >> 1) & 3) << 4));
    int rowB = wn * 64 + f * 16 + fr;
    rbaddr[f] = rowB * 64 + ((fq * 16) ^ (((rowB >> 1) & 3) << 4));
  }

  f32x4 acc[4][4];
  const f32x4 zero = {0.f, 0.f, 0.f, 0.f};
#pragma unroll
  for (int i = 0; i < 4; ++i)
#pragma unroll
    for (int j = 0; j < 4; ++j) acc[i][j] = zero;

  const u16* Abase = A + (size_t)m0 * Dz;
  const u16* Bbase = Wt + (size_t)n0 * Dz;

  const int NKT = Dz / 32;   // 24
  // prologue: stage tile 0 into buf 0 (4 loads/wave)
#pragma unroll
  for (int c = 0; c < 2; ++c) {
    GLL16(Abase + aoff[c], (char*)As[0] + (wid * 2 + c) * 1024);
    GLL16(Bbase + aoff[c], (char*)Bs[0] + (wid * 2 + c) * 1024);
  }
  int cur = 0;

  for (int kt = 0; kt < NKT; ++kt) {
    int nx = cur + 1; if (nx == 3) nx = 0;
    if (kt + 1 < NKT) {
      int ke = (kt + 1) * 32;
#pragma unroll
      for (int c = 0; c < 2; ++c) {
        GLL16(Abase + ke + aoff[c], (char*)As[nx] + (wid * 2 + c) * 1024);
        GLL16(Bbase + ke + aoff[c], (char*)Bs[nx] + (wid * 2 + c) * 1024);
      }
      asm volatile("s_waitcnt vmcnt(4)" ::: "memory");  // tile kt landed; kt+1 in flight
    } else {
      asm volatile("s_waitcnt vmcnt(0)" ::: "memory");
    }
    __builtin_amdgcn_s_barrier();
    __builtin_amdgcn_sched_barrier(0);

    bf16x8 af[4], bf[4];
#pragma unroll
    for (int f = 0; f < 4; ++f) {
      af[f] = *(const bf16x8*)((const char*)As[cur] + raddr[f]);
      bf[f] = *(const bf16x8*)((const char*)Bs[cur] + rbaddr[f]);
    }
    __builtin_amdgcn_s_setprio(1);
#pragma unroll
    for (int i = 0; i < 4; ++i)
#pragma unroll
      for (int j = 0; j < 4; ++j)
        acc[i][j] = mfma16(af[i], bf[j], acc[i][j]);
    __builtin_amdgcn_s_setprio(0);
    cur = nx;
  }

  if (mode == 2) {
    float* O = (float*)out;
#pragma unroll
    for (int i = 0; i < 4; ++i) {
      int grow = m0 + wm * 64 + i * 16 + fq * 4;
#pragma unroll
      for (int j = 0; j < 4; ++j) {
        int gcol = n0 + wn * 64 + j * 16 + fr;
        float bv = bias[gcol];
#pragma unroll
        for (int r = 0; r < 4; ++r)
          O[(size_t)(grow + r) * Dz + gcol] = acc[i][j][r] + bv;
      }
    }
  } else {
    u16* O = (u16*)out;
#pragma unroll
    for (int i = 0; i < 4; ++i) {
      int grow = m0 + wm * 64 + i * 16 + fq * 4;
#pragma unroll
      for (int j = 0; j < 4; ++j) {
        int gcol = n0 + wn * 64 + j * 16 + fr;
        float bv = bias[gcol];
        int h = gcol >> 6, dh = gcol & 63;
#pragma unroll
        for (int r = 0; r < 4; ++r) {
          int t = grow + r;
          int b = t >> 11, s = t & 2047;
          float v = (acc[i][j][r] + bv) * oscale;
          if (mode == 0)
            O[((size_t)(b * Hz + h) * Sz + s) * DHz + dh] = f2bf(v);
          else
            O[((size_t)(b * Hz + h) * DHz + dh) * Sz + s] = f2bf(v);
        }
      }
    }
  }
}

// Q is pre-scaled by 1/sqrt(DH) * log2(e) so attention can use raw v_exp_f32 (exp2)
#define QSCALE 0.1803368801111404f   // 0.125 * 1.4426950408889634

__global__ __launch_bounds__(256, 2) void gemm_qkv(
    const u16* __restrict__ qb, const u16* __restrict__ kb, const u16* __restrict__ vb,
    const u16* __restrict__ Wqt, const u16* __restrict__ Wkt, const u16* __restrict__ Wvt,
    const float* __restrict__ bq, const float* __restrict__ bk, const float* __restrict__ bv,
    u16* __restrict__ Qh, u16* __restrict__ Kh, u16* __restrict__ Vt)
{
  __shared__ u16 As[3][128 * 32];
  __shared__ u16 Bs[3][128 * 32];
  const u16* A; const u16* W; const float* bias; u16* out; int mode; float osc;
  if (blockIdx.z == 0)      { A = qb; W = Wqt; bias = bq; out = Qh; mode = 0; osc = QSCALE; }
  else if (blockIdx.z == 1) { A = kb; W = Wkt; bias = bk; out = Kh; mode = 0; osc = 1.f; }
  else                      { A = vb; W = Wvt; bias = bv; out = Vt; mode = 1; osc = 1.f; }
  gemm_core(A, W, bias, out, mode, osc, As, Bs);
}

__global__ __launch_bounds__(256, 2) void gemm_out_k(
    const u16* __restrict__ ctx, const u16* __restrict__ Wot,
    const float* __restrict__ bo, float* __restrict__ out)
{
  __shared__ u16 As[3][128 * 32];
  __shared__ u16 Bs[3][128 * 32];
  gemm_core(ctx, Wot, bo, (void*)out, 2, 1.f, As, Bs);
}

// ---------------- flash attention, causal, PAIRED 32-ROW Q-TILES ----------------
// grid (B*H, NQT2/2) = (24, 32) = 768 blocks of 128 threads (2 waves).
// Block p handles q-tiles {p, 63-p}; stages k-tiles once, feeds both from LDS.
// TRIPLE-buffered K/V with one raw barrier per k-tile and counted vmcnt(8):
// next tile's 8 global_load_lds stay in flight across the barrier (T4), and the
// 3-buffer rotation makes the pre-barrier prefetch write-after-read safe.
__device__ __forceinline__ void stage_kv(const u16* __restrict__ Kg, const u16* __restrict__ Vg,
                                         int kt, u16* Ks, u16* Vs, int wid, int lane) {
#pragma unroll
  for (int c = 0; c < 4; ++c) {
    int off  = (wid * 4 + c) * 1024 + lane * 16;
    int row  = off >> 7;                       // 128B rows (64 bf16)
    int colb = (off & 127) ^ ((row & 7) << 4); // XOR swizzle bits 4-6
    GLL16(Kg + ((size_t)(kt * 64 + row)) * DHz + (colb >> 1), (char*)Ks + (wid * 4 + c) * 1024);
    GLL16(Vg + (size_t)row * Sz + kt * 64 + (colb >> 1),      (char*)Vs + (wid * 4 + c) * 1024);
  }
}

// one 16-row group's work for one staged k-tile
__device__ __forceinline__ void attn_group(
    const bf16x8* aq, const bf16x8 kfr[4][2], const bf16x8 vfr[4][2],
    f32x4* o, float* m_r, float* l_r, char* Pw,
    int qbase, int kt, bool diag, int fq, int fr)
{
  const f32x4 zero = {0.f, 0.f, 0.f, 0.f};
  f32x4 s[4];
#pragma unroll
  for (int j = 0; j < 4; ++j) s[j] = zero;
  __builtin_amdgcn_s_setprio(1);
#pragma unroll
  for (int j = 0; j < 4; ++j)
#pragma unroll
    for (int kk = 0; kk < 2; ++kk)
      s[j] = mfma16(aq[kk], kfr[j][kk], s[j]);
  __builtin_amdgcn_s_setprio(0);

  if (diag) {
#pragma unroll
    for (int j = 0; j < 4; ++j) {
      int keyg = kt * 64 + j * 16 + fr;
#pragma unroll
      for (int r = 0; r < 4; ++r)
        if (keyg > qbase + fq * 4 + r) s[j][r] = -1e30f;
    }
  }

  // per-lane partial row max (cross-lane reduce only when defer triggers)
  float mt[4];
#pragma unroll
  for (int r = 0; r < 4; ++r) mt[r] = s[0][r];
#pragma unroll
  for (int j = 1; j < 4; ++j)
#pragma unroll
    for (int r = 0; r < 4; ++r) mt[r] = fmaxf(mt[r], s[j][r]);

  int nd = 0;
#pragma unroll
  for (int r = 0; r < 4; ++r) nd |= (mt[r] > m_r[r] + 8.f) ? 1 : 0;
  if (__any(nd)) {
#pragma unroll
    for (int msk = 1; msk < 16; msk <<= 1)
#pragma unroll
      for (int r = 0; r < 4; ++r) mt[r] = fmaxf(mt[r], __shfl_xor(mt[r], msk));
#pragma unroll
    for (int r = 0; r < 4; ++r) {
      float mn = fmaxf(m_r[r], mt[r]);
      float alpha = __builtin_amdgcn_exp2f(m_r[r] - mn);
      m_r[r] = mn;
      l_r[r] *= alpha;
#pragma unroll
      for (int i = 0; i < 4; ++i) o[i][r] *= alpha;
    }
  }

  // P = exp2(S - m); per-lane partial l; write P to per-wave LDS (swizzled)
#pragma unroll
  for (int j = 0; j < 4; ++j) {
#pragma unroll
    for (int r = 0; r < 4; ++r) {
      float e = __builtin_amdgcn_exp2f(s[j][r] - m_r[r]);
      l_r[r] += e;
      int qr = fq * 4 + r;
      int key2 = (j * 16 + fr) * 2;
      *(u16*)(Pw + qr * 128 + (key2 ^ ((qr & 7) << 4))) = f2bf(e);
    }
  }

  // O += P V
  __builtin_amdgcn_s_setprio(1);
#pragma unroll
  for (int kk = 0; kk < 2; ++kk) {
    int cbP = (kk * 64 + fq * 16) ^ ((fr & 7) << 4);
    bf16x8 pa = *(const bf16x8*)(Pw + fr * 128 + cbP);
#pragma unroll
    for (int fo = 0; fo < 4; ++fo)
      o[fo] = mfma16(pa, vfr[fo][kk], o[fo]);
  }
  __builtin_amdgcn_s_setprio(0);
}

__global__ __launch_bounds__(128, 2) void attn_kernel(
    const u16* __restrict__ Qh, const u16* __restrict__ Kh,
    const u16* __restrict__ Vt, u16* __restrict__ ctx)
{
  __shared__ u16 Ks[3][64 * 64];     // 24 KB
  __shared__ u16 Vs[3][64 * 64];     // 24 KB
  __shared__ u16 Ps[2 * 16 * 64];    //  4 KB (per-wave P, reused by both groups)
  const int tid = threadIdx.x, wid = tid >> 6, lane = tid & 63;
  const int fq = lane >> 4, fr = lane & 15;
  const int bh = blockIdx.x;
  const int p = blockIdx.y;            // pair index 0..31 (heaviest staging first)
  const int b = bh / Hz, h = bh % Hz;
  const int qb0 = p * 32 + wid * 16;                 // low q-tile rows (this wave)
  const int qb1 = (NQT2 - 1 - p) * 32 + wid * 16;    // high q-tile rows
  const int nkt = ((NQT2 - p) * 32 + 63) / 64;       // staged k-tiles (covers high)
  const int nlo = ((p + 1) * 32 + 63) / 64;          // low group active iterations

  const u16* Kg = Kh + (size_t)bh * Sz * DHz;
  const u16* Vg = Vt + (size_t)bh * DHz * Sz;
  const u16* Qg = Qh + (size_t)bh * Sz * DHz;

  bf16x8 aq[2][2];
#pragma unroll
  for (int kk = 0; kk < 2; ++kk) {
    aq[0][kk] = *(const bf16x8*)(Qg + (qb0 + fr) * DHz + kk * 32 + fq * 8);
    aq[1][kk] = *(const bf16x8*)(Qg + (qb1 + fr) * DHz + kk * 32 + fq * 8);
  }

  const f32x4 zero = {0.f, 0.f, 0.f, 0.f};
  f32x4 o[2][4];
#pragma unroll
  for (int g = 0; g < 2; ++g)
#pragma unroll
    for (int i = 0; i < 4; ++i) o[g][i] = zero;
  float m_r[2][4], l_r[2][4];
#pragma unroll
  for (int g = 0; g < 2; ++g)
#pragma unroll
    for (int r = 0; r < 4; ++r) { m_r[g][r] = -1e30f; l_r[g][r] = 0.f; }

  char* Pw = (char*)(Ps + wid * 16 * 64);

  stage_kv(Kg, Vg, 0, Ks[0], Vs[0], wid, lane);
  int cur = 0;

  for (int kt = 0; kt < nkt; ++kt) {
    int nx = cur + 1; if (nx == 3) nx = 0;
    // issue next tile's staging FIRST (into the third buffer -> no WAR race),
    // then counted wait: tile kt's 8 loads done; tile kt+1's stay in flight.
    if (kt + 1 < nkt) {
      stage_kv(Kg, Vg, kt + 1, Ks[nx], Vs[nx], wid, lane);
      asm volatile("s_waitcnt vmcnt(8)" ::: "memory");
    } else {
      asm volatile("s_waitcnt vmcnt(0)" ::: "memory");
    }
    __builtin_amdgcn_s_barrier();
    __builtin_amdgcn_sched_barrier(0);

    const char* Kb = (const char*)Ks[cur];
    const char* Vb = (const char*)Vs[cur];

    // shared K fragments
    bf16x8 kfr[4][2];
#pragma unroll
    for (int j = 0; j < 4; ++j) {
      int rowK = j * 16 + fr;
#pragma unroll
      for (int kk = 0; kk < 2; ++kk)
        kfr[j][kk] = *(const bf16x8*)(Kb + rowK * 128 + ((kk * 64 + fq * 16) ^ ((rowK & 7) << 4)));
    }
    // shared V fragments
    bf16x8 vfr[4][2];
#pragma unroll
    for (int fo = 0; fo < 4; ++fo) {
      int rowV = fo * 16 + fr;
#pragma unroll
      for (int kk = 0; kk < 2; ++kk)
        vfr[fo][kk] = *(const bf16x8*)(Vb + rowV * 128 + ((kk * 64 + fq * 16) ^ ((rowV & 7) << 4)));
    }

    if (kt < nlo)
      attn_group(aq[0], kfr, vfr, o[0], m_r[0], l_r[0], Pw, qb0, kt, kt == nlo - 1, fq, fr);
    attn_group(aq[1], kfr, vfr, o[1], m_r[1], l_r[1], Pw, qb1, kt, kt == nkt - 1, fq, fr);

    cur = nx;
  }

  // final l reduce (once) + normalize + write ctx [B,S,D] bf16
#pragma unroll
  for (int msk = 1; msk < 16; msk <<= 1)
#pragma unroll
    for (int g = 0; g < 2; ++g)
#pragma unroll
      for (int r = 0; r < 4; ++r) l_r[g][r] += __shfl_xor(l_r[g][r], msk);

#pragma unroll
  for (int g = 0; g < 2; ++g) {
    int qb = (g == 0) ? qb0 : qb1;
#pragma unroll
    for (int fo = 0; fo < 4; ++fo) {
      int dh = fo * 16 + fr;
#pragma unroll
      for (int r = 0; r < 4; ++r) {
        int qg = qb + fq * 4 + r;
        ctx[((size_t)b * Sz + qg) * Dz + h * DHz + dh] = f2bf(o[g][fo][r] / l_r[g][r]);
      }
    }
  }
}

// ---------------- launch ----------------
extern "C" void kernel_launch(void* const* d_in, const int* in_sizes, int n_in,
                              void* d_out, int out_size, void* d_ws, size_t ws_size,
                              hipStream_t stream) {
  const float* q  = (const float*)d_in[0];
  const float* k  = (const float*)d_in[1];
  const float* v  = (const float*)d_in[2];
  const float* Wq = (const float*)d_in[3];
  const float* bq = (const float*)d_in[4];
  const float* Wk = (const float*)d_in[5];
  const float* bk = (const float*)d_in[6];
  const float* Wv = (const float*)d_in[7];
  const float* bv = (const float*)d_in[8];
  const float* Wo = (const float*)d_in[9];
  const float* bo = (const float*)d_in[10];
  float* out = (float*)d_out;

  char* ws = (char*)d_ws;
  size_t off = 0;
  auto alloc = [&](size_t bytes) {
    void* p = ws + off;
    off += (bytes + 255) & ~(size_t)255;
    return p;
  };
  u16* qb  = (u16*)alloc((size_t)Mz * Dz * 2);
  u16* kb  = (u16*)alloc((size_t)Mz * Dz * 2);
  u16* vb  = (u16*)alloc((size_t)Mz * Dz * 2);
  u16* Wqt = (u16*)alloc((size_t)Dz * Dz * 2);
  u16* Wkt = (u16*)alloc((size_t)Dz * Dz * 2);
  u16* Wvt = (u16*)alloc((size_t)Dz * Dz * 2);
  u16* Wot = (u16*)alloc((size_t)Dz * Dz * 2);
  u16* Qh  = (u16*)alloc((size_t)Bz * Hz * Sz * DHz * 2);
  u16* Kh  = (u16*)alloc((size_t)Bz * Hz * Sz * DHz * 2);
  u16* Vtr = (u16*)alloc((size_t)Bz * Hz * DHz * Sz * 2);
  u16* ctx = (u16*)alloc((size_t)Mz * Dz * 2);

  int n8 = Mz * Dz / 8;
  int cblk = (n8 + 255) / 256;
  cvt3_kernel<<<dim3(cblk, 3), 256, 0, stream>>>(q, k, v, qb, kb, vb, n8);

  wtrans4_kernel<<<dim3(Dz / 32, Dz / 32, 4), 256, 0, stream>>>(
      Wq, Wk, Wv, Wo, Wqt, Wkt, Wvt, Wot);

  gemm_qkv<<<dim3(Mz / 128, Dz / 128, 3), 256, 0, stream>>>(
      qb, kb, vb, Wqt, Wkt, Wvt, bq, bk, bv, Qh, Kh, Vtr);

  attn_kernel<<<dim3(Bz * Hz, NQT2 / 2), 128, 0, stream>>>(Qh, Kh, Vtr, ctx);

  gemm_out_k<<<dim3(Mz / 128, Dz / 128), 256, 0, stream>>>(ctx, Wot, bo, out);
}